// Round 3
// baseline (314.014 us; speedup 1.0000x reference)
//
#include <hip/hip_runtime.h>

typedef __attribute__((ext_vector_type(8))) short bf16x8;
typedef __attribute__((ext_vector_type(8))) unsigned short u16x8;
typedef __attribute__((ext_vector_type(4))) float f32x4;

#define MFMA16 __builtin_amdgcn_mfma_f32_16x16x32_bf16

constexpr int Bc = 4, Lc = 2048, Hc = 16, Dc = 64;
// (1/sqrt(64)) * log2(e)
constexpr float SCL = 0.18033688011112042f;

__device__ __forceinline__ unsigned short f2bf(float f) {
  unsigned u = __float_as_uint(f);
  u += 0x7fff + ((u >> 16) & 1);   // RNE
  return (unsigned short)(u >> 16);
}

__device__ __forceinline__ float fexp2(float x) {
  return __builtin_amdgcn_exp2f(x);
}

__device__ __forceinline__ unsigned cvtpk(float a, float b) {
  unsigned r;
  asm("v_cvt_pk_bf16_f32 %0, %1, %2" : "=v"(r) : "v"(a), "v"(b));
  return r;   // [15:0]=bf16(a), [31:16]=bf16(b)
}

__device__ __forceinline__ void glds16(const char* g, char* l) {
  __builtin_amdgcn_global_load_lds(
      (const __attribute__((address_space(1))) unsigned*)g,
      (__attribute__((address_space(3))) unsigned*)l, 16, 0, 0);
}

// ---------------------------------------------------------------------------
// Pre-pass: build bf16 blobs in workspace (exact LDS images, pre-swizzled).
//   KB blob (head,tile): [64 k][128 B] rows, byte (2d)^((k&7)<<4) = K[k][d]
//   VB blob (head,tile): [64 d][128 B] rows, byte (2k)^((d&7)<<4) = V[k][d]
// ---------------------------------------------------------------------------
__global__ __launch_bounds__(256)
void prep_kernel(const float* __restrict__ Kg, const float* __restrict__ Vg,
                 char* __restrict__ KB, char* __restrict__ VB) {
  __shared__ __align__(16) short vt[64 * 72];

  const int bid = blockIdx.x;
  const int bh = bid >> 5;
  const int t  = bid & 31;
  const int b  = bh >> 4;
  const int h  = bh & 15;

  const int tid = threadIdx.x;
  const int r   = tid >> 2;
  const int seg = (tid & 3) * 16;

  const size_t srow = ((size_t)((b * Lc + t * 64 + r) * Hc + h)) * Dc + seg;

  {
    const float* kp = Kg + srow;
    float4 c0 = *reinterpret_cast<const float4*>(kp + 0);
    float4 c1 = *reinterpret_cast<const float4*>(kp + 4);
    float4 c2 = *reinterpret_cast<const float4*>(kp + 8);
    float4 c3 = *reinterpret_cast<const float4*>(kp + 12);
    u16x8 w0, w1;
    w0[0] = f2bf(c0.x); w0[1] = f2bf(c0.y); w0[2] = f2bf(c0.z); w0[3] = f2bf(c0.w);
    w0[4] = f2bf(c1.x); w0[5] = f2bf(c1.y); w0[6] = f2bf(c1.z); w0[7] = f2bf(c1.w);
    w1[0] = f2bf(c2.x); w1[1] = f2bf(c2.y); w1[2] = f2bf(c2.z); w1[3] = f2bf(c2.w);
    w1[4] = f2bf(c3.x); w1[5] = f2bf(c3.y); w1[6] = f2bf(c3.z); w1[7] = f2bf(c3.w);
    char* dst = KB + ((size_t)(bh * 32 + t)) * 8192 + r * 128;
    const int swz = (r & 7) << 4;
    *reinterpret_cast<u16x8*>(dst + ((seg * 2) ^ swz)) = w0;
    *reinterpret_cast<u16x8*>(dst + ((seg * 2 + 16) ^ swz)) = w1;
  }

  {
    const float* vp = Vg + srow;
    float4 v0 = *reinterpret_cast<const float4*>(vp + 0);
    float4 v1 = *reinterpret_cast<const float4*>(vp + 4);
    float4 v2 = *reinterpret_cast<const float4*>(vp + 8);
    float4 v3 = *reinterpret_cast<const float4*>(vp + 12);
    float vv[16];
    vv[0] = v0.x; vv[1] = v0.y; vv[2] = v0.z; vv[3] = v0.w;
    vv[4] = v1.x; vv[5] = v1.y; vv[6] = v1.z; vv[7] = v1.w;
    vv[8] = v2.x; vv[9] = v2.y; vv[10] = v2.z; vv[11] = v2.w;
    vv[12] = v3.x; vv[13] = v3.y; vv[14] = v3.z; vv[15] = v3.w;
#pragma unroll
    for (int j = 0; j < 16; ++j)
      vt[(seg + j) * 72 + r] = (short)f2bf(vv[j]);
  }
  __syncthreads();

  {
    const int d  = tid >> 2;
    const int sk = (tid & 3) * 16;
    u16x8 a0 = *reinterpret_cast<const u16x8*>(vt + d * 72 + sk);
    u16x8 a1 = *reinterpret_cast<const u16x8*>(vt + d * 72 + sk + 8);
    char* dst = VB + ((size_t)(bh * 32 + t)) * 8192 + d * 128;
    const int swz = (d & 7) << 4;
    *reinterpret_cast<u16x8*>(dst + ((sk * 2) ^ swz)) = a0;
    *reinterpret_cast<u16x8*>(dst + ((sk * 2 + 16) ^ swz)) = a1;
  }
}

// ---------------------------------------------------------------------------
// softmax + P-fragment build for one 64x16(q) score set
// ---------------------------------------------------------------------------
__device__ __forceinline__ void sm_tile(
    f32x4 (&s)[4], float& m_run, float& l_run, f32x4 (&o)[4], bf16x8 (&pf)[2],
    int qrow, bool diag, int kv0, int hi4, int srcA, int srcB, bool up) {
  float vmax = -3.0e38f;
#pragma unroll
  for (int ks = 0; ks < 4; ++ks) {
#pragma unroll
    for (int i = 0; i < 4; ++i) {
      float x = s[ks][i];
      if (diag) {
        const int kg = kv0 + ks * 16 + hi4 * 4 + i;
        if (kg > qrow) x = -3.0e38f;
      }
      s[ks][i] = x;
      vmax = fmaxf(vmax, x);
    }
  }
  vmax = fmaxf(vmax, __shfl_xor(vmax, 16));
  vmax = fmaxf(vmax, __shfl_xor(vmax, 32));
  const float m_new = fmaxf(m_run, vmax);
  const float alpha = fexp2(m_run - m_new);

  float rsum = 0.f;
  unsigned pk2[4][2];
#pragma unroll
  for (int ks = 0; ks < 4; ++ks) {
    const float p0 = fexp2(s[ks][0] - m_new);
    const float p1 = fexp2(s[ks][1] - m_new);
    const float p2 = fexp2(s[ks][2] - m_new);
    const float p3 = fexp2(s[ks][3] - m_new);
    rsum += (p0 + p1) + (p2 + p3);
    pk2[ks][0] = cvtpk(p0, p1);
    pk2[ks][1] = cvtpk(p2, p3);
  }
  rsum += __shfl_xor(rsum, 16);
  rsum += __shfl_xor(rsum, 32);
  l_run = l_run * alpha + rsum;
  m_run = m_new;
#pragma unroll
  for (int dt = 0; dt < 4; ++dt) {
    o[dt][0] *= alpha; o[dt][1] *= alpha; o[dt][2] *= alpha; o[dt][3] *= alpha;
  }

#pragma unroll
  for (int c2 = 0; c2 < 2; ++c2) {
    const unsigned A0x = (unsigned)__shfl((int)pk2[2 * c2][0], srcA);
    const unsigned A0y = (unsigned)__shfl((int)pk2[2 * c2][1], srcA);
    const unsigned A1x = (unsigned)__shfl((int)pk2[2 * c2][0], srcB);
    const unsigned A1y = (unsigned)__shfl((int)pk2[2 * c2][1], srcB);
    const unsigned B0x = (unsigned)__shfl((int)pk2[2 * c2 + 1][0], srcA);
    const unsigned B0y = (unsigned)__shfl((int)pk2[2 * c2 + 1][1], srcA);
    const unsigned B1x = (unsigned)__shfl((int)pk2[2 * c2 + 1][0], srcB);
    const unsigned B1y = (unsigned)__shfl((int)pk2[2 * c2 + 1][1], srcB);
    union { unsigned u[4]; bf16x8 v; } cvt;
    cvt.u[0] = up ? B0x : A0x;
    cvt.u[1] = up ? B0y : A0y;
    cvt.u[2] = up ? B1x : A1x;
    cvt.u[3] = up ? B1y : A1y;
    pf[c2] = cvt.v;
  }
}

// ---------------------------------------------------------------------------
// Flash attention, paired q-tiles (qt, 31-qt): perfectly balanced 33 score
// tiles per block; K/V staged once and shared by both q-sets.
// ---------------------------------------------------------------------------
__global__ __launch_bounds__(256, 4)
void fattn3_kernel(const float* __restrict__ Qg, const char* __restrict__ KB,
                   const char* __restrict__ VB, float* __restrict__ Og) {
  __shared__ __align__(128) char smem[32768];   // 2 bufs x (K 8K + V 8K)

  // 1024 blocks, 8 XCDs -> each XCD gets 8 contiguous heads (all 16 pairs).
  const int p    = blockIdx.x;
  const int wk   = (p & 7) * 128 + (p >> 3);
  const int head = wk >> 4;
  const int pq   = wk & 15;
  const int qtA  = pq;           // small tile
  const int qtB  = 31 - pq;      // large tile
  const int b    = head >> 4;
  const int h    = head & 15;

  const int tid = threadIdx.x;
  const int w   = tid >> 6;
  const int l   = tid & 63;
  const int lo  = l & 15;
  const int hi4 = l >> 4;
  const int swzA = (lo & 7) << 4;
  const int srcA = lo + ((l & 16) << 1);
  const int srcB = srcA + 16;
  const bool up  = (l & 32) != 0;

  // ---- Q fragments, pre-scaled by softmax scale ----
  const int qrowA = qtA * 64 + w * 16 + lo;
  const int qrowB = qtB * 64 + w * 16 + lo;
  bf16x8 qfA[2], qfB[2];
  {
    const float* qpA = Qg + ((size_t)((b * Lc + qrowA) * Hc + h)) * Dc;
    const float* qpB = Qg + ((size_t)((b * Lc + qrowB) * Hc + h)) * Dc;
#pragma unroll
    for (int dc = 0; dc < 2; ++dc) {
      float4 a0 = *reinterpret_cast<const float4*>(qpA + dc * 32 + hi4 * 8);
      float4 a1 = *reinterpret_cast<const float4*>(qpA + dc * 32 + hi4 * 8 + 4);
      float4 b0 = *reinterpret_cast<const float4*>(qpB + dc * 32 + hi4 * 8);
      float4 b1 = *reinterpret_cast<const float4*>(qpB + dc * 32 + hi4 * 8 + 4);
      union { unsigned u[4]; bf16x8 v; } fa, fb;
      fa.u[0] = cvtpk(a0.x * SCL, a0.y * SCL);
      fa.u[1] = cvtpk(a0.z * SCL, a0.w * SCL);
      fa.u[2] = cvtpk(a1.x * SCL, a1.y * SCL);
      fa.u[3] = cvtpk(a1.z * SCL, a1.w * SCL);
      fb.u[0] = cvtpk(b0.x * SCL, b0.y * SCL);
      fb.u[1] = cvtpk(b0.z * SCL, b0.w * SCL);
      fb.u[2] = cvtpk(b1.x * SCL, b1.y * SCL);
      fb.u[3] = cvtpk(b1.z * SCL, b1.w * SCL);
      qfA[dc] = fa.v;
      qfB[dc] = fb.v;
    }
  }

  f32x4 oA[4], oB[4];
#pragma unroll
  for (int dt = 0; dt < 4; ++dt) {
    oA[dt][0] = 0.f; oA[dt][1] = 0.f; oA[dt][2] = 0.f; oA[dt][3] = 0.f;
    oB[dt][0] = 0.f; oB[dt][1] = 0.f; oB[dt][2] = 0.f; oB[dt][3] = 0.f;
  }
  float mA = -3.0e38f, lA = 0.0f, mB = -3.0e38f, lB = 0.0f;

  const char* kbase = KB + ((size_t)head * 32) * 8192;
  const char* vbase = VB + ((size_t)head * 32) * 8192;
  const int wo = w * 1024 + l * 16;
  const int wl = w * 1024;

  auto stage = [&](int bufi, int kt) {
    const char* kb = kbase + (size_t)kt * 8192;
    const char* vb = vbase + (size_t)kt * 8192;
    char* dK = smem + bufi * 16384;
    char* dV = dK + 8192;
    glds16(kb + wo, dK + wl);
    glds16(kb + 4096 + wo, dK + 4096 + wl);
    glds16(vb + wo, dV + wl);
    glds16(vb + 4096 + wo, dV + 4096 + wl);
  };

  const int nkt = qtB + 1;
  int buf = 0;
  stage(0, 0);

  for (int kt = 0; kt < nkt; ++kt) {
    if (kt + 1 < nkt) {
      stage(buf ^ 1, kt + 1);
      asm volatile("s_waitcnt vmcnt(4)" ::: "memory");
    } else {
      asm volatile("s_waitcnt vmcnt(0)" ::: "memory");
    }
    __builtin_amdgcn_s_barrier();

    const char* smK = smem + buf * 16384;
    const char* smV = smK + 8192;
    const int kv0 = kt * 64;
    const bool doA = (kt <= qtA);

    // ---- S^T = K * Q^T for both q-sets; K fragments read once ----
    f32x4 sA[4], sB[4];
#pragma unroll
    for (int ks = 0; ks < 4; ++ks) {
      const int rb = (ks * 16 + lo) * 128;
      bf16x8 a0 = *reinterpret_cast<const bf16x8*>(smK + rb + ((hi4 * 16) ^ swzA));
      bf16x8 a1 = *reinterpret_cast<const bf16x8*>(smK + rb + ((64 + hi4 * 16) ^ swzA));
      f32x4 c; c[0] = 0.f; c[1] = 0.f; c[2] = 0.f; c[3] = 0.f;
      c = MFMA16(a0, qfB[0], c, 0, 0, 0);
      c = MFMA16(a1, qfB[1], c, 0, 0, 0);
      sB[ks] = c;
      if (doA) {
        f32x4 d; d[0] = 0.f; d[1] = 0.f; d[2] = 0.f; d[3] = 0.f;
        d = MFMA16(a0, qfA[0], d, 0, 0, 0);
        d = MFMA16(a1, qfA[1], d, 0, 0, 0);
        sA[ks] = d;
      }
    }

    bf16x8 pfA[2], pfB[2];
    sm_tile(sB, mB, lB, oB, pfB, qrowB, kt == qtB, kv0, hi4, srcA, srcB, up);
    if (doA)
      sm_tile(sA, mA, lA, oA, pfA, qrowA, kt == qtA, kv0, hi4, srcA, srcB, up);

    // ---- O^T += V^T * P^T for both; V fragments read once ----
#pragma unroll
    for (int dt = 0; dt < 4; ++dt) {
      const int rb = (dt * 16 + lo) * 128;
#pragma unroll
      for (int c2 = 0; c2 < 2; ++c2) {
        bf16x8 vf = *reinterpret_cast<const bf16x8*>(smV + rb + ((c2 * 64 + hi4 * 16) ^ swzA));
        oB[dt] = MFMA16(vf, pfB[c2], oB[dt], 0, 0, 0);
        if (doA) oA[dt] = MFMA16(vf, pfA[c2], oA[dt], 0, 0, 0);
      }
    }

    __syncthreads();
    buf ^= 1;
  }

  // ---- normalize + store both q-sets ----
  {
    const float invA = 1.0f / lA;
    float* opA = Og + ((size_t)((b * Lc + qrowA) * Hc + h)) * Dc;
#pragma unroll
    for (int dt = 0; dt < 4; ++dt) {
      float4 st;
      st.x = oA[dt][0] * invA; st.y = oA[dt][1] * invA;
      st.z = oA[dt][2] * invA; st.w = oA[dt][3] * invA;
      *reinterpret_cast<float4*>(opA + dt * 16 + hi4 * 4) = st;
    }
    const float invB = 1.0f / lB;
    float* opB = Og + ((size_t)((b * Lc + qrowB) * Hc + h)) * Dc;
#pragma unroll
    for (int dt = 0; dt < 4; ++dt) {
      float4 st;
      st.x = oB[dt][0] * invB; st.y = oB[dt][1] * invB;
      st.z = oB[dt][2] * invB; st.w = oB[dt][3] * invB;
      *reinterpret_cast<float4*>(opB + dt * 16 + hi4 * 4) = st;
    }
  }
}

// ---------------------------------------------------------------------------
// Fallback (ws too small): round-1 kernel.
// ---------------------------------------------------------------------------
__global__ __launch_bounds__(256)
void fattn_fallback(const float* __restrict__ Qg, const float* __restrict__ Kg,
                    const float* __restrict__ Vg, float* __restrict__ Og) {
  __shared__ __align__(128) char smem[32768];
  char* smK = smem;
  char* smV = smem + 16384;

  const int bid  = blockIdx.x;
  const int head = bid >> 5;
  const int qt   = bid & 31;
  const int b    = head >> 4;
  const int h    = head & 15;
  const int q0   = qt * 64;

  const int tid = threadIdx.x;
  const int w   = tid >> 6;
  const int l   = tid & 63;
  const int lo  = l & 15;
  const int hi4 = l >> 4;

  const int qrow = q0 + w * 16 + lo;
  const float* qp = Qg + ((size_t)((b * Lc + qrow) * Hc + h)) * Dc;
  bf16x8 qf[2];
#pragma unroll
  for (int dc = 0; dc < 2; ++dc) {
    float4 a = *reinterpret_cast<const float4*>(qp + dc * 32 + hi4 * 8);
    float4 c = *reinterpret_cast<const float4*>(qp + dc * 32 + hi4 * 8 + 4);
    bf16x8 f;
    f[0] = (short)f2bf(a.x); f[1] = (short)f2bf(a.y);
    f[2] = (short)f2bf(a.z); f[3] = (short)f2bf(a.w);
    f[4] = (short)f2bf(c.x); f[5] = (short)f2bf(c.y);
    f[6] = (short)f2bf(c.z); f[7] = (short)f2bf(c.w);
    qf[dc] = f;
  }

  f32x4 o[4];
#pragma unroll
  for (int dt = 0; dt < 4; ++dt) { o[dt][0] = 0.f; o[dt][1] = 0.f; o[dt][2] = 0.f; o[dt][3] = 0.f; }
  float m_run = -3.0e38f, l_run = 0.0f;

  const int sk   = tid >> 2;
  const int sd   = (tid & 3) * 16;
  const int swzK = (sk & 7) << 4;
  const int swzA = (lo & 7) << 4;

  const int nkt = qt + 1;
  for (int kt = 0; kt < nkt; ++kt) {
    const int kv0 = kt * 64;
    __syncthreads();
    {
      const float* kpr = Kg + ((size_t)((b * Lc + kv0 + sk) * Hc + h)) * Dc + sd;
      float4 c0 = *reinterpret_cast<const float4*>(kpr + 0);
      float4 c1 = *reinterpret_cast<const float4*>(kpr + 4);
      float4 c2 = *reinterpret_cast<const float4*>(kpr + 8);
      float4 c3 = *reinterpret_cast<const float4*>(kpr + 12);
      u16x8 w0, w1;
      w0[0] = f2bf(c0.x); w0[1] = f2bf(c0.y); w0[2] = f2bf(c0.z); w0[3] = f2bf(c0.w);
      w0[4] = f2bf(c1.x); w0[5] = f2bf(c1.y); w0[6] = f2bf(c1.z); w0[7] = f2bf(c1.w);
      w1[0] = f2bf(c2.x); w1[1] = f2bf(c2.y); w1[2] = f2bf(c2.z); w1[3] = f2bf(c2.w);
      w1[4] = f2bf(c3.x); w1[5] = f2bf(c3.y); w1[6] = f2bf(c3.z); w1[7] = f2bf(c3.w);
      *reinterpret_cast<u16x8*>(smK + sk * 128 + ((sd * 2) ^ swzK)) = w0;
      *reinterpret_cast<u16x8*>(smK + sk * 128 + ((sd * 2 + 16) ^ swzK)) = w1;

      const float* vpr = Vg + ((size_t)((b * Lc + kv0 + sk) * Hc + h)) * Dc + sd;
      float4 v0 = *reinterpret_cast<const float4*>(vpr + 0);
      float4 v1 = *reinterpret_cast<const float4*>(vpr + 4);
      float4 v2 = *reinterpret_cast<const float4*>(vpr + 8);
      float4 v3 = *reinterpret_cast<const float4*>(vpr + 12);
      float vv[16];
      vv[0] = v0.x; vv[1] = v0.y; vv[2] = v0.z; vv[3] = v0.w;
      vv[4] = v1.x; vv[5] = v1.y; vv[6] = v1.z; vv[7] = v1.w;
      vv[8] = v2.x; vv[9] = v2.y; vv[10] = v2.z; vv[11] = v2.w;
      vv[12] = v3.x; vv[13] = v3.y; vv[14] = v3.z; vv[15] = v3.w;
#pragma unroll
      for (int j = 0; j < 16; ++j) {
        const int d = sd + j;
        *reinterpret_cast<unsigned short*>(smV + d * 128 + ((sk * 2) ^ ((j & 7) << 4))) = f2bf(vv[j]);
      }
    }
    __syncthreads();

    f32x4 s[4];
#pragma unroll
    for (int ks = 0; ks < 4; ++ks) {
      const int rb = (ks * 16 + lo) * 128;
      bf16x8 a0 = *reinterpret_cast<const bf16x8*>(smK + rb + ((hi4 * 16) ^ swzA));
      bf16x8 a1 = *reinterpret_cast<const bf16x8*>(smK + rb + ((64 + hi4 * 16) ^ swzA));
      f32x4 c; c[0] = 0.f; c[1] = 0.f; c[2] = 0.f; c[3] = 0.f;
      c = MFMA16(a0, qf[0], c, 0, 0, 0);
      c = MFMA16(a1, qf[1], c, 0, 0, 0);
      s[ks] = c;
    }

    const bool diag = (kt == nkt - 1);
    float vmax = -3.0e38f;
#pragma unroll
    for (int ks = 0; ks < 4; ++ks) {
#pragma unroll
      for (int i = 0; i < 4; ++i) {
        float x = s[ks][i] * SCL;
        if (diag) {
          const int kg = kv0 + ks * 16 + hi4 * 4 + i;
          if (kg > qrow) x = -3.0e38f;
        }
        s[ks][i] = x;
        vmax = fmaxf(vmax, x);
      }
    }
    vmax = fmaxf(vmax, __shfl_xor(vmax, 16));
    vmax = fmaxf(vmax, __shfl_xor(vmax, 32));
    const float m_new = fmaxf(m_run, vmax);
    const float alpha = fexp2(m_run - m_new);

    float rsum = 0.f;
    unsigned pk2[4][2];
#pragma unroll
    for (int ks = 0; ks < 4; ++ks) {
      const float p0 = fexp2(s[ks][0] - m_new);
      const float p1 = fexp2(s[ks][1] - m_new);
      const float p2 = fexp2(s[ks][2] - m_new);
      const float p3 = fexp2(s[ks][3] - m_new);
      rsum += (p0 + p1) + (p2 + p3);
      pk2[ks][0] = (unsigned)f2bf(p0) | ((unsigned)f2bf(p1) << 16);
      pk2[ks][1] = (unsigned)f2bf(p2) | ((unsigned)f2bf(p3) << 16);
    }
    rsum += __shfl_xor(rsum, 16);
    rsum += __shfl_xor(rsum, 32);
    l_run = l_run * alpha + rsum;
    m_run = m_new;
#pragma unroll
    for (int dt = 0; dt < 4; ++dt) {
      o[dt][0] *= alpha; o[dt][1] *= alpha; o[dt][2] *= alpha; o[dt][3] *= alpha;
    }

    const int srcA = lo + ((l & 16) << 1);
    const int srcB = srcA + 16;
    const bool up = (l & 32) != 0;
    bf16x8 pf[2];
#pragma unroll
    for (int c2 = 0; c2 < 2; ++c2) {
      const unsigned A0x = (unsigned)__shfl((int)pk2[2 * c2][0], srcA);
      const unsigned A0y = (unsigned)__shfl((int)pk2[2 * c2][1], srcA);
      const unsigned A1x = (unsigned)__shfl((int)pk2[2 * c2][0], srcB);
      const unsigned A1y = (unsigned)__shfl((int)pk2[2 * c2][1], srcB);
      const unsigned B0x = (unsigned)__shfl((int)pk2[2 * c2 + 1][0], srcA);
      const unsigned B0y = (unsigned)__shfl((int)pk2[2 * c2 + 1][1], srcA);
      const unsigned B1x = (unsigned)__shfl((int)pk2[2 * c2 + 1][0], srcB);
      const unsigned B1y = (unsigned)__shfl((int)pk2[2 * c2 + 1][1], srcB);
      union { unsigned u[4]; bf16x8 v; } cvt;
      cvt.u[0] = up ? B0x : A0x;
      cvt.u[1] = up ? B0y : A0y;
      cvt.u[2] = up ? B1x : A1x;
      cvt.u[3] = up ? B1y : A1y;
      pf[c2] = cvt.v;
    }

#pragma unroll
    for (int dt = 0; dt < 4; ++dt) {
      const int rb = (dt * 16 + lo) * 128;
#pragma unroll
      for (int c2 = 0; c2 < 2; ++c2) {
        bf16x8 vf = *reinterpret_cast<const bf16x8*>(smV + rb + ((c2 * 64 + hi4 * 16) ^ swzA));
        o[dt] = MFMA16(vf, pf[c2], o[dt], 0, 0, 0);
      }
    }
  }

  const float inv = 1.0f / l_run;
  float* op = Og + ((size_t)((b * Lc + qrow) * Hc + h)) * Dc;
#pragma unroll
  for (int dt = 0; dt < 4; ++dt) {
    float4 st;
    st.x = o[dt][0] * inv; st.y = o[dt][1] * inv;
    st.z = o[dt][2] * inv; st.w = o[dt][3] * inv;
    *reinterpret_cast<float4*>(op + dt * 16 + hi4 * 4) = st;
  }
}

extern "C" void kernel_launch(void* const* d_in, const int* in_sizes, int n_in,
                              void* d_out, int out_size, void* d_ws, size_t ws_size,
                              hipStream_t stream) {
  const float* Qg = (const float*)d_in[0];
  const float* Kg = (const float*)d_in[1];
  const float* Vg = (const float*)d_in[2];
  float* Og = (float*)d_out;

  const size_t blob_bytes = (size_t)64 * 32 * 8192;   // 16.78 MB per tensor
  if (ws_size >= 2 * blob_bytes) {
    char* KB = (char*)d_ws;
    char* VB = KB + blob_bytes;
    hipLaunchKernelGGL(prep_kernel, dim3(2048), dim3(256), 0, stream, Kg, Vg, KB, VB);
    hipLaunchKernelGGL(fattn3_kernel, dim3(1024), dim3(256), 0, stream, Qg, KB, VB, Og);
  } else {
    hipLaunchKernelGGL(fattn_fallback, dim3(2048), dim3(256), 0, stream, Qg, Kg, Vg, Og);
  }
}

// Round 5
// 126.773 us; speedup vs baseline: 2.4770x; 2.4770x over previous
//
#include <hip/hip_runtime.h>

typedef __attribute__((ext_vector_type(8))) short bf16x8;
typedef __attribute__((ext_vector_type(8))) unsigned short u16x8;
typedef __attribute__((ext_vector_type(4))) float f32x4;

#define MFMA16 __builtin_amdgcn_mfma_f32_16x16x32_bf16

constexpr int Bc = 4, Lc = 2048, Hc = 16, Dc = 64;
// (1/sqrt(64)) * log2(e)
constexpr float SCL = 0.18033688011112042f;

__device__ __forceinline__ unsigned short f2bf(float f) {
  unsigned u = __float_as_uint(f);
  u += 0x7fff + ((u >> 16) & 1);   // RNE
  return (unsigned short)(u >> 16);
}

__device__ __forceinline__ float fexp2(float x) {
  return __builtin_amdgcn_exp2f(x);
}

__device__ __forceinline__ unsigned cvtpk(float a, float b) {
  unsigned r;
  asm("v_cvt_pk_bf16_f32 %0, %1, %2" : "=v"(r) : "v"(a), "v"(b));
  return r;   // [15:0]=bf16(a), [31:16]=bf16(b)
}

__device__ __forceinline__ void glds16(const char* g, char* l) {
  __builtin_amdgcn_global_load_lds(
      (const __attribute__((address_space(1))) unsigned*)g,
      (__attribute__((address_space(3))) unsigned*)l, 16, 0, 0);
}

// ---------------------------------------------------------------------------
// Pre-pass: build bf16 blobs in workspace (exact LDS images, pre-swizzled).
//   KB blob (head,tile): [64 k][128 B] rows, byte (2d)^((k&7)<<4) = K[k][d]
//   VB blob (head,tile): [64 d][128 B] rows, byte (2k)^((d&7)<<4) = V[k][d]
// ---------------------------------------------------------------------------
__global__ __launch_bounds__(256)
void prep_kernel(const float* __restrict__ Kg, const float* __restrict__ Vg,
                 char* __restrict__ KB, char* __restrict__ VB) {
  __shared__ __align__(16) short vt[64 * 72];

  const int bid = blockIdx.x;
  const int bh = bid >> 5;
  const int t  = bid & 31;
  const int b  = bh >> 4;
  const int h  = bh & 15;

  const int tid = threadIdx.x;
  const int r   = tid >> 2;
  const int seg = (tid & 3) * 16;

  const size_t srow = ((size_t)((b * Lc + t * 64 + r) * Hc + h)) * Dc + seg;

  {
    const float* kp = Kg + srow;
    float4 c0 = *reinterpret_cast<const float4*>(kp + 0);
    float4 c1 = *reinterpret_cast<const float4*>(kp + 4);
    float4 c2 = *reinterpret_cast<const float4*>(kp + 8);
    float4 c3 = *reinterpret_cast<const float4*>(kp + 12);
    u16x8 w0, w1;
    w0[0] = f2bf(c0.x); w0[1] = f2bf(c0.y); w0[2] = f2bf(c0.z); w0[3] = f2bf(c0.w);
    w0[4] = f2bf(c1.x); w0[5] = f2bf(c1.y); w0[6] = f2bf(c1.z); w0[7] = f2bf(c1.w);
    w1[0] = f2bf(c2.x); w1[1] = f2bf(c2.y); w1[2] = f2bf(c2.z); w1[3] = f2bf(c2.w);
    w1[4] = f2bf(c3.x); w1[5] = f2bf(c3.y); w1[6] = f2bf(c3.z); w1[7] = f2bf(c3.w);
    char* dst = KB + ((size_t)(bh * 32 + t)) * 8192 + r * 128;
    const int swz = (r & 7) << 4;
    *reinterpret_cast<u16x8*>(dst + ((seg * 2) ^ swz)) = w0;
    *reinterpret_cast<u16x8*>(dst + ((seg * 2 + 16) ^ swz)) = w1;
  }

  {
    const float* vp = Vg + srow;
    float4 v0 = *reinterpret_cast<const float4*>(vp + 0);
    float4 v1 = *reinterpret_cast<const float4*>(vp + 4);
    float4 v2 = *reinterpret_cast<const float4*>(vp + 8);
    float4 v3 = *reinterpret_cast<const float4*>(vp + 12);
    float vv[16];
    vv[0] = v0.x; vv[1] = v0.y; vv[2] = v0.z; vv[3] = v0.w;
    vv[4] = v1.x; vv[5] = v1.y; vv[6] = v1.z; vv[7] = v1.w;
    vv[8] = v2.x; vv[9] = v2.y; vv[10] = v2.z; vv[11] = v2.w;
    vv[12] = v3.x; vv[13] = v3.y; vv[14] = v3.z; vv[15] = v3.w;
#pragma unroll
    for (int j = 0; j < 16; ++j)
      vt[(seg + j) * 72 + r] = (short)f2bf(vv[j]);
  }
  __syncthreads();

  {
    const int d  = tid >> 2;
    const int sk = (tid & 3) * 16;
    u16x8 a0 = *reinterpret_cast<const u16x8*>(vt + d * 72 + sk);
    u16x8 a1 = *reinterpret_cast<const u16x8*>(vt + d * 72 + sk + 8);
    char* dst = VB + ((size_t)(bh * 32 + t)) * 8192 + d * 128;
    const int swz = (d & 7) << 4;
    *reinterpret_cast<u16x8*>(dst + ((sk * 2) ^ swz)) = a0;
    *reinterpret_cast<u16x8*>(dst + ((sk * 2 + 16) ^ swz)) = a1;
  }
}

// ---------------------------------------------------------------------------
// Flash attention, paired q-tiles (qt, 31-qt): uniform 33 tile-units/block,
// 1024 blocks. A and B q-sets processed SEQUENTIALLY per kv-tile to keep
// peak register pressure ~110 VGPR (round-3's shared-fragment form spilled).
// Round-3-proven softmax math (always-rescale, store at end).
// ---------------------------------------------------------------------------
__global__ __launch_bounds__(256)
void fattn5_kernel(const float* __restrict__ Qg, const char* __restrict__ KB,
                   const char* __restrict__ VB, float* __restrict__ Og) {
  __shared__ __align__(128) char smem[32768];   // 2 bufs x (K 8K + V 8K)

  // 1024 blocks, 8 XCDs -> each XCD gets 8 contiguous heads (all 16 pairs).
  const int p    = blockIdx.x;
  const int wk   = (p & 7) * 128 + (p >> 3);
  const int head = wk >> 4;
  const int pq   = wk & 15;
  const int qtA  = pq;           // small tile
  const int qtB  = 31 - pq;      // large tile
  const int b    = head >> 4;
  const int h    = head & 15;

  const int tid = threadIdx.x;
  const int w   = tid >> 6;
  const int l   = tid & 63;
  const int lo  = l & 15;
  const int hi4 = l >> 4;
  const int swzA = (lo & 7) << 4;
  const int srcA = lo + ((l & 16) << 1);
  const int srcB = srcA + 16;
  const bool up  = (l & 32) != 0;

  // ---- Q fragments, pre-scaled by softmax scale ----
  const int qrowA = qtA * 64 + w * 16 + lo;
  const int qrowB = qtB * 64 + w * 16 + lo;
  bf16x8 qfA[2], qfB[2];
  {
    const float* qpA = Qg + ((size_t)((b * Lc + qrowA) * Hc + h)) * Dc;
    const float* qpB = Qg + ((size_t)((b * Lc + qrowB) * Hc + h)) * Dc;
#pragma unroll
    for (int dc = 0; dc < 2; ++dc) {
      float4 a0 = *reinterpret_cast<const float4*>(qpA + dc * 32 + hi4 * 8);
      float4 a1 = *reinterpret_cast<const float4*>(qpA + dc * 32 + hi4 * 8 + 4);
      float4 b0 = *reinterpret_cast<const float4*>(qpB + dc * 32 + hi4 * 8);
      float4 b1 = *reinterpret_cast<const float4*>(qpB + dc * 32 + hi4 * 8 + 4);
      union { unsigned u[4]; bf16x8 v; } fa, fb;
      fa.u[0] = cvtpk(a0.x * SCL, a0.y * SCL);
      fa.u[1] = cvtpk(a0.z * SCL, a0.w * SCL);
      fa.u[2] = cvtpk(a1.x * SCL, a1.y * SCL);
      fa.u[3] = cvtpk(a1.z * SCL, a1.w * SCL);
      fb.u[0] = cvtpk(b0.x * SCL, b0.y * SCL);
      fb.u[1] = cvtpk(b0.z * SCL, b0.w * SCL);
      fb.u[2] = cvtpk(b1.x * SCL, b1.y * SCL);
      fb.u[3] = cvtpk(b1.z * SCL, b1.w * SCL);
      qfA[dc] = fa.v;
      qfB[dc] = fb.v;
    }
  }

  f32x4 oA[4], oB[4];
#pragma unroll
  for (int dt = 0; dt < 4; ++dt) {
    oA[dt][0] = 0.f; oA[dt][1] = 0.f; oA[dt][2] = 0.f; oA[dt][3] = 0.f;
    oB[dt][0] = 0.f; oB[dt][1] = 0.f; oB[dt][2] = 0.f; oB[dt][3] = 0.f;
  }
  float mA = -3.0e38f, lA = 0.0f, mB = -3.0e38f, lB = 0.0f;

  const char* kbase = KB + ((size_t)head * 32) * 8192;
  const char* vbase = VB + ((size_t)head * 32) * 8192;
  const int wo = w * 1024 + l * 16;
  const int wl = w * 1024;

  auto stage = [&](int bufi, int kt) {
    const char* kb = kbase + (size_t)kt * 8192;
    const char* vb = vbase + (size_t)kt * 8192;
    char* dK = smem + bufi * 16384;
    char* dV = dK + 8192;
    glds16(kb + wo, dK + wl);
    glds16(kb + 4096 + wo, dK + 4096 + wl);
    glds16(vb + wo, dV + wl);
    glds16(vb + 4096 + wo, dV + 4096 + wl);
  };

  // One full q-set unit: QK^T -> softmax -> PV (round-3 math, always-rescale)
  auto process = [&](const bf16x8 (&qf)[2], f32x4 (&o)[4], float& m_run,
                     float& l_run, int qrow, bool diag, int kv0,
                     const char* smK, const char* smV) {
    f32x4 s[4];
#pragma unroll
    for (int ks = 0; ks < 4; ++ks) {
      const int rb = (ks * 16 + lo) * 128;
      bf16x8 a0 = *reinterpret_cast<const bf16x8*>(smK + rb + ((hi4 * 16) ^ swzA));
      bf16x8 a1 = *reinterpret_cast<const bf16x8*>(smK + rb + ((64 + hi4 * 16) ^ swzA));
      f32x4 c; c[0] = 0.f; c[1] = 0.f; c[2] = 0.f; c[3] = 0.f;
      c = MFMA16(a0, qf[0], c, 0, 0, 0);
      c = MFMA16(a1, qf[1], c, 0, 0, 0);
      s[ks] = c;
    }

    float vmax = -3.0e38f;
#pragma unroll
    for (int ks = 0; ks < 4; ++ks) {
#pragma unroll
      for (int i = 0; i < 4; ++i) {
        float x = s[ks][i];
        if (diag) {
          const int kg = kv0 + ks * 16 + hi4 * 4 + i;
          if (kg > qrow) x = -3.0e38f;
        }
        s[ks][i] = x;
        vmax = fmaxf(vmax, x);
      }
    }
    vmax = fmaxf(vmax, __shfl_xor(vmax, 16));
    vmax = fmaxf(vmax, __shfl_xor(vmax, 32));
    const float m_new = fmaxf(m_run, vmax);
    const float alpha = fexp2(m_run - m_new);

    float rsum = 0.f;
    unsigned pk2[4][2];
#pragma unroll
    for (int ks = 0; ks < 4; ++ks) {
      const float p0 = fexp2(s[ks][0] - m_new);
      const float p1 = fexp2(s[ks][1] - m_new);
      const float p2 = fexp2(s[ks][2] - m_new);
      const float p3 = fexp2(s[ks][3] - m_new);
      rsum += (p0 + p1) + (p2 + p3);
      pk2[ks][0] = cvtpk(p0, p1);
      pk2[ks][1] = cvtpk(p2, p3);
    }
    rsum += __shfl_xor(rsum, 16);
    rsum += __shfl_xor(rsum, 32);
    l_run = l_run * alpha + rsum;
    m_run = m_new;
#pragma unroll
    for (int dt = 0; dt < 4; ++dt) {
      o[dt][0] *= alpha; o[dt][1] *= alpha; o[dt][2] *= alpha; o[dt][3] *= alpha;
    }

    bf16x8 pf[2];
#pragma unroll
    for (int c2 = 0; c2 < 2; ++c2) {
      const unsigned A0x = (unsigned)__shfl((int)pk2[2 * c2][0], srcA);
      const unsigned A0y = (unsigned)__shfl((int)pk2[2 * c2][1], srcA);
      const unsigned A1x = (unsigned)__shfl((int)pk2[2 * c2][0], srcB);
      const unsigned A1y = (unsigned)__shfl((int)pk2[2 * c2][1], srcB);
      const unsigned B0x = (unsigned)__shfl((int)pk2[2 * c2 + 1][0], srcA);
      const unsigned B0y = (unsigned)__shfl((int)pk2[2 * c2 + 1][1], srcA);
      const unsigned B1x = (unsigned)__shfl((int)pk2[2 * c2 + 1][0], srcB);
      const unsigned B1y = (unsigned)__shfl((int)pk2[2 * c2 + 1][1], srcB);
      union { unsigned u[4]; bf16x8 v; } cvt;
      cvt.u[0] = up ? B0x : A0x;
      cvt.u[1] = up ? B0y : A0y;
      cvt.u[2] = up ? B1x : A1x;
      cvt.u[3] = up ? B1y : A1y;
      pf[c2] = cvt.v;
    }

#pragma unroll
    for (int dt = 0; dt < 4; ++dt) {
      const int rb = (dt * 16 + lo) * 128;
#pragma unroll
      for (int c2 = 0; c2 < 2; ++c2) {
        bf16x8 vf = *reinterpret_cast<const bf16x8*>(smV + rb + ((c2 * 64 + hi4 * 16) ^ swzA));
        o[dt] = MFMA16(vf, pf[c2], o[dt], 0, 0, 0);
      }
    }
  };

  const int nkt = qtB + 1;
  int buf = 0;
  stage(0, 0);

  for (int kt = 0; kt < nkt; ++kt) {
    if (kt + 1 < nkt) {
      stage(buf ^ 1, kt + 1);
      asm volatile("s_waitcnt vmcnt(4)" ::: "memory");
    } else {
      asm volatile("s_waitcnt vmcnt(0)" ::: "memory");
    }
    __builtin_amdgcn_s_barrier();

    const char* smK = smem + buf * 16384;
    const char* smV = smK + 8192;
    const int kv0 = kt * 64;

    process(qfB, oB, mB, lB, qrowB, kt == qtB, kv0, smK, smV);
    if (kt <= qtA)
      process(qfA, oA, mA, lA, qrowA, kt == qtA, kv0, smK, smV);

    __syncthreads();
    buf ^= 1;
  }

  // ---- normalize + store both q-sets ----
  {
    const float invA = 1.0f / lA;
    float* opA = Og + ((size_t)((b * Lc + qrowA) * Hc + h)) * Dc;
#pragma unroll
    for (int dt = 0; dt < 4; ++dt) {
      float4 st;
      st.x = oA[dt][0] * invA; st.y = oA[dt][1] * invA;
      st.z = oA[dt][2] * invA; st.w = oA[dt][3] * invA;
      *reinterpret_cast<float4*>(opA + dt * 16 + hi4 * 4) = st;
    }
    const float invB = 1.0f / lB;
    float* opB = Og + ((size_t)((b * Lc + qrowB) * Hc + h)) * Dc;
#pragma unroll
    for (int dt = 0; dt < 4; ++dt) {
      float4 st;
      st.x = oB[dt][0] * invB; st.y = oB[dt][1] * invB;
      st.z = oB[dt][2] * invB; st.w = oB[dt][3] * invB;
      *reinterpret_cast<float4*>(opB + dt * 16 + hi4 * 4) = st;
    }
  }
}

// ---------------------------------------------------------------------------
// Fallback (ws too small): round-1 kernel.
// ---------------------------------------------------------------------------
__global__ __launch_bounds__(256)
void fattn_fallback(const float* __restrict__ Qg, const float* __restrict__ Kg,
                    const float* __restrict__ Vg, float* __restrict__ Og) {
  __shared__ __align__(128) char smem[32768];
  char* smK = smem;
  char* smV = smem + 16384;

  const int bid  = blockIdx.x;
  const int head = bid >> 5;
  const int qt   = bid & 31;
  const int b    = head >> 4;
  const int h    = head & 15;
  const int q0   = qt * 64;

  const int tid = threadIdx.x;
  const int w   = tid >> 6;
  const int l   = tid & 63;
  const int lo  = l & 15;
  const int hi4 = l >> 4;

  const int qrow = q0 + w * 16 + lo;
  const float* qp = Qg + ((size_t)((b * Lc + qrow) * Hc + h)) * Dc;
  bf16x8 qf[2];
#pragma unroll
  for (int dc = 0; dc < 2; ++dc) {
    float4 a = *reinterpret_cast<const float4*>(qp + dc * 32 + hi4 * 8);
    float4 c = *reinterpret_cast<const float4*>(qp + dc * 32 + hi4 * 8 + 4);
    bf16x8 f;
    f[0] = (short)f2bf(a.x); f[1] = (short)f2bf(a.y);
    f[2] = (short)f2bf(a.z); f[3] = (short)f2bf(a.w);
    f[4] = (short)f2bf(c.x); f[5] = (short)f2bf(c.y);
    f[6] = (short)f2bf(c.z); f[7] = (short)f2bf(c.w);
    qf[dc] = f;
  }

  f32x4 o[4];
#pragma unroll
  for (int dt = 0; dt < 4; ++dt) { o[dt][0] = 0.f; o[dt][1] = 0.f; o[dt][2] = 0.f; o[dt][3] = 0.f; }
  float m_run = -3.0e38f, l_run = 0.0f;

  const int sk   = tid >> 2;
  const int sd   = (tid & 3) * 16;
  const int swzK = (sk & 7) << 4;
  const int swzA = (lo & 7) << 4;

  const int nkt = qt + 1;
  for (int kt = 0; kt < nkt; ++kt) {
    const int kv0 = kt * 64;
    __syncthreads();
    {
      const float* kpr = Kg + ((size_t)((b * Lc + kv0 + sk) * Hc + h)) * Dc + sd;
      float4 c0 = *reinterpret_cast<const float4*>(kpr + 0);
      float4 c1 = *reinterpret_cast<const float4*>(kpr + 4);
      float4 c2 = *reinterpret_cast<const float4*>(kpr + 8);
      float4 c3 = *reinterpret_cast<const float4*>(kpr + 12);
      u16x8 w0, w1;
      w0[0] = f2bf(c0.x); w0[1] = f2bf(c0.y); w0[2] = f2bf(c0.z); w0[3] = f2bf(c0.w);
      w0[4] = f2bf(c1.x); w0[5] = f2bf(c1.y); w0[6] = f2bf(c1.z); w0[7] = f2bf(c1.w);
      w1[0] = f2bf(c2.x); w1[1] = f2bf(c2.y); w1[2] = f2bf(c2.z); w1[3] = f2bf(c2.w);
      w1[4] = f2bf(c3.x); w1[5] = f2bf(c3.y); w1[6] = f2bf(c3.z); w1[7] = f2bf(c3.w);
      *reinterpret_cast<u16x8*>(smK + sk * 128 + ((sd * 2) ^ swzK)) = w0;
      *reinterpret_cast<u16x8*>(smK + sk * 128 + ((sd * 2 + 16) ^ swzK)) = w1;

      const float* vpr = Vg + ((size_t)((b * Lc + kv0 + sk) * Hc + h)) * Dc + sd;
      float4 v0 = *reinterpret_cast<const float4*>(vpr + 0);
      float4 v1 = *reinterpret_cast<const float4*>(vpr + 4);
      float4 v2 = *reinterpret_cast<const float4*>(vpr + 8);
      float4 v3 = *reinterpret_cast<const float4*>(vpr + 12);
      float vv[16];
      vv[0] = v0.x; vv[1] = v0.y; vv[2] = v0.z; vv[3] = v0.w;
      vv[4] = v1.x; vv[5] = v1.y; vv[6] = v1.z; vv[7] = v1.w;
      vv[8] = v2.x; vv[9] = v2.y; vv[10] = v2.z; vv[11] = v2.w;
      vv[12] = v3.x; vv[13] = v3.y; vv[14] = v3.z; vv[15] = v3.w;
#pragma unroll
      for (int j = 0; j < 16; ++j) {
        const int d = sd + j;
        *reinterpret_cast<unsigned short*>(smV + d * 128 + ((sk * 2) ^ ((j & 7) << 4))) = f2bf(vv[j]);
      }
    }
    __syncthreads();

    f32x4 s[4];
#pragma unroll
    for (int ks = 0; ks < 4; ++ks) {
      const int rb = (ks * 16 + lo) * 128;
      bf16x8 a0 = *reinterpret_cast<const bf16x8*>(smK + rb + ((hi4 * 16) ^ swzA));
      bf16x8 a1 = *reinterpret_cast<const bf16x8*>(smK + rb + ((64 + hi4 * 16) ^ swzA));
      f32x4 c; c[0] = 0.f; c[1] = 0.f; c[2] = 0.f; c[3] = 0.f;
      c = MFMA16(a0, qf[0], c, 0, 0, 0);
      c = MFMA16(a1, qf[1], c, 0, 0, 0);
      s[ks] = c;
    }

    const bool diag = (kt == nkt - 1);
    float vmax = -3.0e38f;
#pragma unroll
    for (int ks = 0; ks < 4; ++ks) {
#pragma unroll
      for (int i = 0; i < 4; ++i) {
        float x = s[ks][i] * SCL;
        if (diag) {
          const int kg = kv0 + ks * 16 + hi4 * 4 + i;
          if (kg > qrow) x = -3.0e38f;
        }
        s[ks][i] = x;
        vmax = fmaxf(vmax, x);
      }
    }
    vmax = fmaxf(vmax, __shfl_xor(vmax, 16));
    vmax = fmaxf(vmax, __shfl_xor(vmax, 32));
    const float m_new = fmaxf(m_run, vmax);
    const float alpha = fexp2(m_run - m_new);

    float rsum = 0.f;
    unsigned pk2[4][2];
#pragma unroll
    for (int ks = 0; ks < 4; ++ks) {
      const float p0 = fexp2(s[ks][0] - m_new);
      const float p1 = fexp2(s[ks][1] - m_new);
      const float p2 = fexp2(s[ks][2] - m_new);
      const float p3 = fexp2(s[ks][3] - m_new);
      rsum += (p0 + p1) + (p2 + p3);
      pk2[ks][0] = (unsigned)f2bf(p0) | ((unsigned)f2bf(p1) << 16);
      pk2[ks][1] = (unsigned)f2bf(p2) | ((unsigned)f2bf(p3) << 16);
    }
    rsum += __shfl_xor(rsum, 16);
    rsum += __shfl_xor(rsum, 32);
    l_run = l_run * alpha + rsum;
    m_run = m_new;
#pragma unroll
    for (int dt = 0; dt < 4; ++dt) {
      o[dt][0] *= alpha; o[dt][1] *= alpha; o[dt][2] *= alpha; o[dt][3] *= alpha;
    }

    const int srcA = lo + ((l & 16) << 1);
    const int srcB = srcA + 16;
    const bool up = (l & 32) != 0;
    bf16x8 pf[2];
#pragma unroll
    for (int c2 = 0; c2 < 2; ++c2) {
      const unsigned A0x = (unsigned)__shfl((int)pk2[2 * c2][0], srcA);
      const unsigned A0y = (unsigned)__shfl((int)pk2[2 * c2][1], srcA);
      const unsigned A1x = (unsigned)__shfl((int)pk2[2 * c2][0], srcB);
      const unsigned A1y = (unsigned)__shfl((int)pk2[2 * c2][1], srcB);
      const unsigned B0x = (unsigned)__shfl((int)pk2[2 * c2 + 1][0], srcA);
      const unsigned B0y = (unsigned)__shfl((int)pk2[2 * c2 + 1][1], srcA);
      const unsigned B1x = (unsigned)__shfl((int)pk2[2 * c2 + 1][0], srcB);
      const unsigned B1y = (unsigned)__shfl((int)pk2[2 * c2 + 1][1], srcB);
      union { unsigned u[4]; bf16x8 v; } cvt;
      cvt.u[0] = up ? B0x : A0x;
      cvt.u[1] = up ? B0y : A0y;
      cvt.u[2] = up ? B1x : A1x;
      cvt.u[3] = up ? B1y : A1y;
      pf[c2] = cvt.v;
    }

#pragma unroll
    for (int dt = 0; dt < 4; ++dt) {
      const int rb = (dt * 16 + lo) * 128;
#pragma unroll
      for (int c2 = 0; c2 < 2; ++c2) {
        bf16x8 vf = *reinterpret_cast<const bf16x8*>(smV + rb + ((c2 * 64 + hi4 * 16) ^ swzA));
        o[dt] = MFMA16(vf, pf[c2], o[dt], 0, 0, 0);
      }
    }
  }

  const float inv = 1.0f / l_run;
  float* op = Og + ((size_t)((b * Lc + qrow) * Hc + h)) * Dc;
#pragma unroll
  for (int dt = 0; dt < 4; ++dt) {
    float4 st;
    st.x = o[dt][0] * inv; st.y = o[dt][1] * inv;
    st.z = o[dt][2] * inv; st.w = o[dt][3] * inv;
    *reinterpret_cast<float4*>(op + dt * 16 + hi4 * 4) = st;
  }
}

extern "C" void kernel_launch(void* const* d_in, const int* in_sizes, int n_in,
                              void* d_out, int out_size, void* d_ws, size_t ws_size,
                              hipStream_t stream) {
  const float* Qg = (const float*)d_in[0];
  const float* Kg = (const float*)d_in[1];
  const float* Vg = (const float*)d_in[2];
  float* Og = (float*)d_out;

  const size_t blob_bytes = (size_t)64 * 32 * 8192;   // 16.78 MB per tensor
  if (ws_size >= 2 * blob_bytes) {
    char* KB = (char*)d_ws;
    char* VB = KB + blob_bytes;
    hipLaunchKernelGGL(prep_kernel, dim3(2048), dim3(256), 0, stream, Kg, Vg, KB, VB);
    hipLaunchKernelGGL(fattn5_kernel, dim3(1024), dim3(256), 0, stream, Qg, KB, VB, Og);
  } else {
    hipLaunchKernelGGL(fattn_fallback, dim3(2048), dim3(256), 0, stream, Qg, Kg, Vg, Og);
  }
}

// Round 7
// 86.378 us; speedup vs baseline: 3.6353x; 1.4676x over previous
//
#include <hip/hip_runtime.h>

typedef __attribute__((ext_vector_type(8))) short bf16x8;
typedef __attribute__((ext_vector_type(8))) unsigned short u16x8;
typedef __attribute__((ext_vector_type(4))) float f32x4;
typedef __attribute__((ext_vector_type(16))) float f32x16;

#define MFMA32 __builtin_amdgcn_mfma_f32_32x32x16_bf16
#define MFMA16 __builtin_amdgcn_mfma_f32_16x16x32_bf16

constexpr int Bc = 4, Lc = 2048, Hc = 16, Dc = 64;
// (1/sqrt(64)) * log2(e)
constexpr float SCL = 0.18033688011112042f;

__device__ __forceinline__ unsigned short f2bf(float f) {
  unsigned u = __float_as_uint(f);
  u += 0x7fff + ((u >> 16) & 1);   // RNE
  return (unsigned short)(u >> 16);
}

__device__ __forceinline__ float fexp2(float x) {
  return __builtin_amdgcn_exp2f(x);
}

__device__ __forceinline__ unsigned cvtpk(float a, float b) {
  unsigned r;
  asm("v_cvt_pk_bf16_f32 %0, %1, %2" : "=v"(r) : "v"(a), "v"(b));
  return r;   // [15:0]=bf16(a), [31:16]=bf16(b)  (verified r3->r5 pass)
}

__device__ __forceinline__ void glds16(const char* g, char* l) {
  __builtin_amdgcn_global_load_lds(
      (const __attribute__((address_space(1))) unsigned*)g,
      (__attribute__((address_space(3))) unsigned*)l, 16, 0, 0);
}

// ---------------------------------------------------------------------------
// Pre-pass: build FRAGMENT-MAJOR bf16 blobs (exact LDS images, lane-linear,
// conflict-free ds_read_b128 in the attention kernel — no swizzle).
//   K blob chunk (kt2,kc), lane L, 16B: K[kv0+kt2*32+(L&31)][16kc+8(L>>5)+j]
//   V blob chunk (dt2,kc), lane L, 16B: V[kv0+16kc+8(L>>5)+j][32dt2+(L&31)]
//   chunk offset = ((c2*4+kc)*64 + L)*16, tile blob = 8 KB each.
// ---------------------------------------------------------------------------
__global__ __launch_bounds__(256)
void prep6_kernel(const float* __restrict__ Kg, const float* __restrict__ Vg,
                  char* __restrict__ KB, char* __restrict__ VB) {
  __shared__ __align__(16) short vt[64 * 80];   // V^T staging

  const int bid = blockIdx.x;
  const int bh = bid >> 5;
  const int t  = bid & 31;
  const int b  = bh >> 4;
  const int h  = bh & 15;

  const int tid = threadIdx.x;
  const int r   = tid >> 2;        // 0..63
  const int seg = (tid & 3) * 16;  // 0,16,32,48

  const size_t srow = ((size_t)((b * Lc + t * 64 + r) * Hc + h)) * Dc + seg;
  char* ktile = KB + (size_t)(bh * 32 + t) * 8192;
  char* vtile = VB + (size_t)(bh * 32 + t) * 8192;

  // ---- K: convert + fragment-major write ----
  {
    const float* kp = Kg + srow;
    float4 c0 = *reinterpret_cast<const float4*>(kp + 0);
    float4 c1 = *reinterpret_cast<const float4*>(kp + 4);
    float4 c2 = *reinterpret_cast<const float4*>(kp + 8);
    float4 c3 = *reinterpret_cast<const float4*>(kp + 12);
    union { unsigned u[4]; u16x8 v; } w0, w1;
    w0.u[0] = cvtpk(c0.x, c0.y); w0.u[1] = cvtpk(c0.z, c0.w);
    w0.u[2] = cvtpk(c1.x, c1.y); w0.u[3] = cvtpk(c1.z, c1.w);
    w1.u[0] = cvtpk(c2.x, c2.y); w1.u[1] = cvtpk(c2.z, c2.w);
    w1.u[2] = cvtpk(c3.x, c3.y); w1.u[3] = cvtpk(c3.z, c3.w);
    const int kc   = seg >> 4;
    const int kt2  = r >> 5;
    const int lane = r & 31;
    *reinterpret_cast<u16x8*>(ktile + ((kt2 * 4 + kc) * 64 + lane) * 16) = w0.v;
    *reinterpret_cast<u16x8*>(ktile + ((kt2 * 4 + kc) * 64 + lane + 32) * 16) = w1.v;
  }

  // ---- V: convert + LDS transpose ----
  {
    const float* vp = Vg + srow;
    float4 v0 = *reinterpret_cast<const float4*>(vp + 0);
    float4 v1 = *reinterpret_cast<const float4*>(vp + 4);
    float4 v2 = *reinterpret_cast<const float4*>(vp + 8);
    float4 v3 = *reinterpret_cast<const float4*>(vp + 12);
    float vv[16];
    vv[0] = v0.x; vv[1] = v0.y; vv[2] = v0.z; vv[3] = v0.w;
    vv[4] = v1.x; vv[5] = v1.y; vv[6] = v1.z; vv[7] = v1.w;
    vv[8] = v2.x; vv[9] = v2.y; vv[10] = v2.z; vv[11] = v2.w;
    vv[12] = v3.x; vv[13] = v3.y; vv[14] = v3.z; vv[15] = v3.w;
#pragma unroll
    for (int j = 0; j < 16; ++j)
      vt[(seg + j) * 80 + r] = (short)f2bf(vv[j]);
  }
  __syncthreads();

  // ---- V^T rows -> fragment-major write ----
  {
    const int d    = tid >> 2;
    const int kseg = (tid & 3) * 16;
    u16x8 a0 = *reinterpret_cast<const u16x8*>(vt + d * 80 + kseg);      // kv +0..7
    u16x8 a1 = *reinterpret_cast<const u16x8*>(vt + d * 80 + kseg + 8);  // kv +8..15
    const int dt2  = d >> 5;
    const int kc   = kseg >> 4;
    const int lane = d & 31;
    *reinterpret_cast<u16x8*>(vtile + ((dt2 * 4 + kc) * 64 + lane) * 16) = a0;
    *reinterpret_cast<u16x8*>(vtile + ((dt2 * 4 + kc) * 64 + lane + 32) * 16) = a1;
  }
}

// ---------------------------------------------------------------------------
// Flash attention, 32x32x16 MFMA. 1 block = 128 q-rows (4 waves x 32 q),
// KVBLK=64, double-buffered DMA staging of fragment-major blobs.
// P-fragments built via cvt_pk + __shfl_xor(32) (provably-correct routing).
// qt interleave {m,15-m,m+4,11-m} balances per-CU work.
// ---------------------------------------------------------------------------
__global__ __launch_bounds__(256)
void fattn7_kernel(const float* __restrict__ Qg, const char* __restrict__ KB,
                   const char* __restrict__ VB, float* __restrict__ Og) {
  __shared__ __align__(128) char smem[32768];   // 2 bufs x (K 8K + V 8K)

  const int p  = blockIdx.x;
  const int x  = p & 7;            // XCD (hw round-robin)
  const int sl = p >> 3;           // slot within XCD stream
  const int t  = sl >> 5;          // dispatch round 0..3
  const int c  = sl & 31;          // CU slot
  const int hl = c & 7;
  const int mm = c >> 3;
  const int qt = (t == 0) ? mm : (t == 1) ? 15 - mm : (t == 2) ? mm + 4 : 11 - mm;
  const int head = x * 8 + hl;
  const int b = head >> 4;
  const int h = head & 15;

  const int tid = threadIdx.x;
  const int w   = tid >> 6;        // wave 0..3
  const int l   = tid & 63;
  const int q5  = l & 31;
  const int hp  = l >> 5;          // half 0/1

  const int qrow = qt * 128 + w * 32 + q5;
  const int qmin = qt * 128 + w * 32;
  const int qmax = qmin + 31;

  // ---- Q fragments (B operand: lane q=l&31, k-dim d=16kc+8hp+j), pre-scaled ----
  bf16x8 qf[4];
  {
    const float* qp = Qg + ((size_t)((b * Lc + qrow) * Hc + h)) * Dc;
#pragma unroll
    for (int kc = 0; kc < 4; ++kc) {
      const int d0 = kc * 16 + hp * 8;
      float4 a = *reinterpret_cast<const float4*>(qp + d0);
      float4 bb = *reinterpret_cast<const float4*>(qp + d0 + 4);
      union { unsigned u[4]; bf16x8 v; } f;
      f.u[0] = cvtpk(a.x * SCL, a.y * SCL);
      f.u[1] = cvtpk(a.z * SCL, a.w * SCL);
      f.u[2] = cvtpk(bb.x * SCL, bb.y * SCL);
      f.u[3] = cvtpk(bb.z * SCL, bb.w * SCL);
      qf[kc] = f.v;
    }
  }

  f32x16 o0, o1;
#pragma unroll
  for (int i = 0; i < 16; ++i) { o0[i] = 0.f; o1[i] = 0.f; }
  float m_run = -3.0e38f, l_run = 0.0f;

  const char* kbase = KB + ((size_t)head * 32) * 8192;
  const char* vbase = VB + ((size_t)head * 32) * 8192;
  const int to = tid * 16;         // per-lane global offset
  const int wl = w * 1024;         // wave-uniform LDS base offset

  auto stage = [&](int bufi, int kt) {
    const char* kb = kbase + (size_t)kt * 8192;
    const char* vb = vbase + (size_t)kt * 8192;
    char* dK = smem + bufi * 16384;
    char* dV = dK + 8192;
    glds16(kb + to, dK + wl);
    glds16(kb + 4096 + to, dK + 4096 + wl);
    glds16(vb + to, dV + wl);
    glds16(vb + 4096 + to, dV + 4096 + wl);
  };

  const int nkt = 2 * qt + 2;
  int buf = 0;
  stage(0, 0);

  for (int kt = 0; kt < nkt; ++kt) {
    if (kt + 1 < nkt) {
      stage(buf ^ 1, kt + 1);
      asm volatile("s_waitcnt vmcnt(4)" ::: "memory");
    } else {
      asm volatile("s_waitcnt vmcnt(0)" ::: "memory");
    }
    __builtin_amdgcn_s_barrier();

    const int kv0 = kt * 64;
    if (kv0 <= qmax) {               // wave-uniform skip of fully-masked tiles
      const char* smK = smem + buf * 16384;
      const char* smV = smK + 8192;

      // ---- S^T = K * Q^T (2 kv-subtiles of 32) ----
      f32x16 s0, s1;
#pragma unroll
      for (int i = 0; i < 16; ++i) { s0[i] = 0.f; s1[i] = 0.f; }
#pragma unroll
      for (int kc = 0; kc < 4; ++kc) {
        bf16x8 k0 = *reinterpret_cast<const bf16x8*>(smK + (0 * 4 + kc) * 1024 + l * 16);
        bf16x8 k1 = *reinterpret_cast<const bf16x8*>(smK + (1 * 4 + kc) * 1024 + l * 16);
        s0 = MFMA32(k0, qf[kc], s0, 0, 0, 0);
        s1 = MFMA32(k1, qf[kc], s1, 0, 0, 0);
      }

      float pv[32];
#pragma unroll
      for (int g = 0; g < 16; ++g) { pv[g] = s0[g]; pv[16 + g] = s1[g]; }

      // ---- causal mask (kv row = (g&3)+8*((g>>2)&3)+4hp+32*(g>>4)) ----
      if (kv0 + 63 > qmin) {
#pragma unroll
        for (int g = 0; g < 32; ++g) {
          const int k = (g & 3) + 8 * ((g >> 2) & 3) + 4 * hp + 32 * (g >> 4);
          if (kv0 + k > qrow) pv[g] = -3.0e38f;
        }
      }

      // ---- online softmax (row q=l&31; halves in lanes l and l^32) ----
      float vmax = pv[0];
#pragma unroll
      for (int g = 1; g < 32; ++g) vmax = fmaxf(vmax, pv[g]);
      vmax = fmaxf(vmax, __shfl_xor(vmax, 32));
      const float m_new = fmaxf(m_run, vmax);
      const float alpha = fexp2(m_run - m_new);

      float rsum = 0.f;
#pragma unroll
      for (int g = 0; g < 32; ++g) { pv[g] = fexp2(pv[g] - m_new); rsum += pv[g]; }
      rsum += __shfl_xor(rsum, 32);
      l_run = l_run * alpha + rsum;
      m_run = m_new;
#pragma unroll
      for (int i = 0; i < 16; ++i) { o0[i] *= alpha; o1[i] *= alpha; }

      // ---- P -> PV B-fragments: cvt_pk + shfl_xor(32) + selects ----
      // own regs (hp=0): A=(k 0..3 mod16-grp), B=(k 8..11); hp=1: +4.
      bf16x8 pf[4];
#pragma unroll
      for (int kc = 0; kc < 4; ++kc) {
        const int G = 8 * kc;
        unsigned A0 = cvtpk(pv[G + 0], pv[G + 1]);
        unsigned A1 = cvtpk(pv[G + 2], pv[G + 3]);
        unsigned B0 = cvtpk(pv[G + 4], pv[G + 5]);
        unsigned B1 = cvtpk(pv[G + 6], pv[G + 7]);
        const unsigned t0 = hp ? A0 : B0;     // what the partner lane needs
        const unsigned t1 = hp ? A1 : B1;
        const unsigned x0 = (unsigned)__shfl_xor((int)t0, 32);
        const unsigned x1 = (unsigned)__shfl_xor((int)t1, 32);
        union { unsigned u[4]; bf16x8 v; } f;
        f.u[0] = hp ? x0 : A0;   // hp0: k0,1   hp1: k8,9
        f.u[1] = hp ? x1 : A1;   // hp0: k2,3   hp1: k10,11
        f.u[2] = hp ? B0 : x0;   // hp0: k4,5   hp1: k12,13
        f.u[3] = hp ? B1 : x1;   // hp0: k6,7   hp1: k14,15
        pf[kc] = f.v;
      }

      // ---- O^T += V^T * P^T ----
#pragma unroll
      for (int kc = 0; kc < 4; ++kc) {
        bf16x8 v0 = *reinterpret_cast<const bf16x8*>(smV + (0 * 4 + kc) * 1024 + l * 16);
        bf16x8 v1 = *reinterpret_cast<const bf16x8*>(smV + (1 * 4 + kc) * 1024 + l * 16);
        o0 = MFMA32(v0, pf[kc], o0, 0, 0, 0);
        o1 = MFMA32(v1, pf[kc], o1, 0, 0, 0);
      }
    }

    __syncthreads();
    buf ^= 1;
  }

  // ---- normalize + store: lane q=l&31, d=(reg&3)+8*(reg>>2)+4hp (+32 for o1) ----
  const float inv = 1.0f / l_run;
  float* op = Og + ((size_t)((b * Lc + qrow) * Hc + h)) * Dc;
#pragma unroll
  for (int rq = 0; rq < 4; ++rq) {
    float4 st0, st1;
    st0.x = o0[4 * rq + 0] * inv; st0.y = o0[4 * rq + 1] * inv;
    st0.z = o0[4 * rq + 2] * inv; st0.w = o0[4 * rq + 3] * inv;
    st1.x = o1[4 * rq + 0] * inv; st1.y = o1[4 * rq + 1] * inv;
    st1.z = o1[4 * rq + 2] * inv; st1.w = o1[4 * rq + 3] * inv;
    *reinterpret_cast<float4*>(op + 8 * rq + 4 * hp) = st0;
    *reinterpret_cast<float4*>(op + 32 + 8 * rq + 4 * hp) = st1;
  }
}

// ---------------------------------------------------------------------------
// Fallback (ws too small): round-1/5-proven self-contained kernel.
// ---------------------------------------------------------------------------
__global__ __launch_bounds__(256)
void fattn_fallback(const float* __restrict__ Qg, const float* __restrict__ Kg,
                    const float* __restrict__ Vg, float* __restrict__ Og) {
  __shared__ __align__(128) char smem[32768];
  char* smK = smem;
  char* smV = smem + 16384;

  const int bid  = blockIdx.x;
  const int head = bid >> 5;
  const int qt   = bid & 31;
  const int b    = head >> 4;
  const int h    = head & 15;
  const int q0   = qt * 64;

  const int tid = threadIdx.x;
  const int w   = tid >> 6;
  const int l   = tid & 63;
  const int lo  = l & 15;
  const int hi4 = l >> 4;

  const int qrow = q0 + w * 16 + lo;
  const float* qp = Qg + ((size_t)((b * Lc + qrow) * Hc + h)) * Dc;
  bf16x8 qf[2];
#pragma unroll
  for (int dc = 0; dc < 2; ++dc) {
    float4 a = *reinterpret_cast<const float4*>(qp + dc * 32 + hi4 * 8);
    float4 c = *reinterpret_cast<const float4*>(qp + dc * 32 + hi4 * 8 + 4);
    bf16x8 f;
    f[0] = (short)f2bf(a.x * SCL); f[1] = (short)f2bf(a.y * SCL);
    f[2] = (short)f2bf(a.z * SCL); f[3] = (short)f2bf(a.w * SCL);
    f[4] = (short)f2bf(c.x * SCL); f[5] = (short)f2bf(c.y * SCL);
    f[6] = (short)f2bf(c.z * SCL); f[7] = (short)f2bf(c.w * SCL);
    qf[dc] = f;
  }

  f32x4 o[4];
#pragma unroll
  for (int dt = 0; dt < 4; ++dt) { o[dt][0] = 0.f; o[dt][1] = 0.f; o[dt][2] = 0.f; o[dt][3] = 0.f; }
  float m_run = -3.0e38f, l_run = 0.0f;

  const int sk   = tid >> 2;
  const int sd   = (tid & 3) * 16;
  const int swzK = (sk & 7) << 4;
  const int swzA = (lo & 7) << 4;

  const int nkt = qt + 1;
  for (int kt = 0; kt < nkt; ++kt) {
    const int kv0 = kt * 64;
    __syncthreads();
    {
      const float* kpr = Kg + ((size_t)((b * Lc + kv0 + sk) * Hc + h)) * Dc + sd;
      float4 c0 = *reinterpret_cast<const float4*>(kpr + 0);
      float4 c1 = *reinterpret_cast<const float4*>(kpr + 4);
      float4 c2 = *reinterpret_cast<const float4*>(kpr + 8);
      float4 c3 = *reinterpret_cast<const float4*>(kpr + 12);
      u16x8 w0, w1;
      w0[0] = f2bf(c0.x); w0[1] = f2bf(c0.y); w0[2] = f2bf(c0.z); w0[3] = f2bf(c0.w);
      w0[4] = f2bf(c1.x); w0[5] = f2bf(c1.y); w0[6] = f2bf(c1.z); w0[7] = f2bf(c1.w);
      w1[0] = f2bf(c2.x); w1[1] = f2bf(c2.y); w1[2] = f2bf(c2.z); w1[3] = f2bf(c2.w);
      w1[4] = f2bf(c3.x); w1[5] = f2bf(c3.y); w1[6] = f2bf(c3.z); w1[7] = f2bf(c3.w);
      *reinterpret_cast<u16x8*>(smK + sk * 128 + ((sd * 2) ^ swzK)) = w0;
      *reinterpret_cast<u16x8*>(smK + sk * 128 + ((sd * 2 + 16) ^ swzK)) = w1;

      const float* vpr = Vg + ((size_t)((b * Lc + kv0 + sk) * Hc + h)) * Dc + sd;
      float4 v0 = *reinterpret_cast<const float4*>(vpr + 0);
      float4 v1 = *reinterpret_cast<const float4*>(vpr + 4);
      float4 v2 = *reinterpret_cast<const float4*>(vpr + 8);
      float4 v3 = *reinterpret_cast<const float4*>(vpr + 12);
      float vv[16];
      vv[0] = v0.x; vv[1] = v0.y; vv[2] = v0.z; vv[3] = v0.w;
      vv[4] = v1.x; vv[5] = v1.y; vv[6] = v1.z; vv[7] = v1.w;
      vv[8] = v2.x; vv[9] = v2.y; vv[10] = v2.z; vv[11] = v2.w;
      vv[12] = v3.x; vv[13] = v3.y; vv[14] = v3.z; vv[15] = v3.w;
#pragma unroll
      for (int j = 0; j < 16; ++j) {
        const int d = sd + j;
        *reinterpret_cast<unsigned short*>(smV + d * 128 + ((sk * 2) ^ ((j & 7) << 4))) = f2bf(vv[j]);
      }
    }
    __syncthreads();

    f32x4 s[4];
#pragma unroll
    for (int ks = 0; ks < 4; ++ks) {
      const int rb = (ks * 16 + lo) * 128;
      bf16x8 a0 = *reinterpret_cast<const bf16x8*>(smK + rb + ((hi4 * 16) ^ swzA));
      bf16x8 a1 = *reinterpret_cast<const bf16x8*>(smK + rb + ((64 + hi4 * 16) ^ swzA));
      f32x4 c; c[0] = 0.f; c[1] = 0.f; c[2] = 0.f; c[3] = 0.f;
      c = MFMA16(a0, qf[0], c, 0, 0, 0);
      c = MFMA16(a1, qf[1], c, 0, 0, 0);
      s[ks] = c;
    }

    const bool diag = (kt == nkt - 1);
    float vmax = -3.0e38f;
#pragma unroll
    for (int ks = 0; ks < 4; ++ks) {
#pragma unroll
      for (int i = 0; i < 4; ++i) {
        float x = s[ks][i];
        if (diag) {
          const int kg = kv0 + ks * 16 + hi4 * 4 + i;
          if (kg > qrow) x = -3.0e38f;
        }
        s[ks][i] = x;
        vmax = fmaxf(vmax, x);
      }
    }
    vmax = fmaxf(vmax, __shfl_xor(vmax, 16));
    vmax = fmaxf(vmax, __shfl_xor(vmax, 32));
    const float m_new = fmaxf(m_run, vmax);
    const float alpha = fexp2(m_run - m_new);

    float rsum = 0.f;
    unsigned pk2[4][2];
#pragma unroll
    for (int ks = 0; ks < 4; ++ks) {
      const float p0 = fexp2(s[ks][0] - m_new);
      const float p1 = fexp2(s[ks][1] - m_new);
      const float p2 = fexp2(s[ks][2] - m_new);
      const float p3 = fexp2(s[ks][3] - m_new);
      rsum += (p0 + p1) + (p2 + p3);
      pk2[ks][0] = (unsigned)f2bf(p0) | ((unsigned)f2bf(p1) << 16);
      pk2[ks][1] = (unsigned)f2bf(p2) | ((unsigned)f2bf(p3) << 16);
    }
    rsum += __shfl_xor(rsum, 16);
    rsum += __shfl_xor(rsum, 32);
    l_run = l_run * alpha + rsum;
    m_run = m_new;
#pragma unroll
    for (int dt = 0; dt < 4; ++dt) {
      o[dt][0] *= alpha; o[dt][1] *= alpha; o[dt][2] *= alpha; o[dt][3] *= alpha;
    }

    const int srcA = lo + ((l & 16) << 1);
    const int srcB = srcA + 16;
    const bool up = (l & 32) != 0;
    bf16x8 pf[2];
#pragma unroll
    for (int c2 = 0; c2 < 2; ++c2) {
      const unsigned A0x = (unsigned)__shfl((int)pk2[2 * c2][0], srcA);
      const unsigned A0y = (unsigned)__shfl((int)pk2[2 * c2][1], srcA);
      const unsigned A1x = (unsigned)__shfl((int)pk2[2 * c2][0], srcB);
      const unsigned A1y = (unsigned)__shfl((int)pk2[2 * c2][1], srcB);
      const unsigned B0x = (unsigned)__shfl((int)pk2[2 * c2 + 1][0], srcA);
      const unsigned B0y = (unsigned)__shfl((int)pk2[2 * c2 + 1][1], srcA);
      const unsigned B1x = (unsigned)__shfl((int)pk2[2 * c2 + 1][0], srcB);
      const unsigned B1y = (unsigned)__shfl((int)pk2[2 * c2 + 1][1], srcB);
      union { unsigned u[4]; bf16x8 v; } cvt;
      cvt.u[0] = up ? B0x : A0x;
      cvt.u[1] = up ? B0y : A0y;
      cvt.u[2] = up ? B1x : A1x;
      cvt.u[3] = up ? B1y : A1y;
      pf[c2] = cvt.v;
    }

#pragma unroll
    for (int dt = 0; dt < 4; ++dt) {
      const int rb = (dt * 16 + lo) * 128;
#pragma unroll
      for (int c2 = 0; c2 < 2; ++c2) {
        bf16x8 vf = *reinterpret_cast<const bf16x8*>(smV + rb + ((c2 * 64 + hi4 * 16) ^ swzA));
        o[dt] = MFMA16(vf, pf[c2], o[dt], 0, 0, 0);
      }
    }
  }

  const float inv = 1.0f / l_run;
  float* op = Og + ((size_t)((b * Lc + qrow) * Hc + h)) * Dc;
#pragma unroll
  for (int dt = 0; dt < 4; ++dt) {
    float4 st;
    st.x = o[dt][0] * inv; st.y = o[dt][1] * inv;
    st.z = o[dt][2] * inv; st.w = o[dt][3] * inv;
    *reinterpret_cast<float4*>(op + dt * 16 + hi4 * 4) = st;
  }
}

extern "C" void kernel_launch(void* const* d_in, const int* in_sizes, int n_in,
                              void* d_out, int out_size, void* d_ws, size_t ws_size,
                              hipStream_t stream) {
  const float* Qg = (const float*)d_in[0];
  const float* Kg = (const float*)d_in[1];
  const float* Vg = (const float*)d_in[2];
  float* Og = (float*)d_out;

  const size_t blob_bytes = (size_t)64 * 32 * 8192;   // 16.78 MB per tensor
  if (ws_size >= 2 * blob_bytes) {
    char* KB = (char*)d_ws;
    char* VB = KB + blob_bytes;
    hipLaunchKernelGGL(prep6_kernel, dim3(2048), dim3(256), 0, stream, Kg, Vg, KB, VB);
    hipLaunchKernelGGL(fattn7_kernel, dim3(1024), dim3(256), 0, stream, Qg, KB, VB, Og);
  } else {
    hipLaunchKernelGGL(fattn_fallback, dim3(2048), dim3(256), 0, stream, Qg, Kg, Vg, Og);
  }
}

// Round 8
// 82.808 us; speedup vs baseline: 3.7921x; 1.0431x over previous
//
#include <hip/hip_runtime.h>

typedef __attribute__((ext_vector_type(8))) short bf16x8;
typedef __attribute__((ext_vector_type(8))) unsigned short u16x8;
typedef __attribute__((ext_vector_type(4))) float f32x4;
typedef __attribute__((ext_vector_type(16))) float f32x16;

#define MFMA32 __builtin_amdgcn_mfma_f32_32x32x16_bf16
#define MFMA16 __builtin_amdgcn_mfma_f32_16x16x32_bf16

constexpr int Bc = 4, Lc = 2048, Hc = 16, Dc = 64;
// (1/sqrt(64)) * log2(e)
constexpr float SCL = 0.18033688011112042f;

__device__ __forceinline__ unsigned short f2bf(float f) {
  unsigned u = __float_as_uint(f);
  u += 0x7fff + ((u >> 16) & 1);   // RNE
  return (unsigned short)(u >> 16);
}

__device__ __forceinline__ float fexp2(float x) {
  return __builtin_amdgcn_exp2f(x);
}

__device__ __forceinline__ unsigned cvtpk(float a, float b) {
  unsigned r;
  asm("v_cvt_pk_bf16_f32 %0, %1, %2" : "=v"(r) : "v"(a), "v"(b));
  return r;   // [15:0]=bf16(a), [31:16]=bf16(b)
}

__device__ __forceinline__ void glds16(const char* g, char* l) {
  __builtin_amdgcn_global_load_lds(
      (const __attribute__((address_space(1))) unsigned*)g,
      (__attribute__((address_space(3))) unsigned*)l, 16, 0, 0);
}

// ---------------------------------------------------------------------------
// Pre-pass: build FRAGMENT-MAJOR bf16 blobs (exact LDS images, lane-linear,
// conflict-free ds_read_b128 in the attention kernel — no swizzle).
//   K blob chunk (kt2,kc), lane L, 16B: K[kv0+kt2*32+(L&31)][16kc+8(L>>5)+j]
//   V blob chunk (dt2,kc), lane L, 16B: V[kv0+16kc+8(L>>5)+j][32dt2+(L&31)]
// ---------------------------------------------------------------------------
__global__ __launch_bounds__(256)
void prep6_kernel(const float* __restrict__ Kg, const float* __restrict__ Vg,
                  char* __restrict__ KB, char* __restrict__ VB) {
  __shared__ __align__(16) short vt[64 * 80];   // V^T staging

  const int bid = blockIdx.x;
  const int bh = bid >> 5;
  const int t  = bid & 31;
  const int b  = bh >> 4;
  const int h  = bh & 15;

  const int tid = threadIdx.x;
  const int r   = tid >> 2;        // 0..63
  const int seg = (tid & 3) * 16;  // 0,16,32,48

  const size_t srow = ((size_t)((b * Lc + t * 64 + r) * Hc + h)) * Dc + seg;
  char* ktile = KB + (size_t)(bh * 32 + t) * 8192;
  char* vtile = VB + (size_t)(bh * 32 + t) * 8192;

  // ---- K: convert + fragment-major write ----
  {
    const float* kp = Kg + srow;
    float4 c0 = *reinterpret_cast<const float4*>(kp + 0);
    float4 c1 = *reinterpret_cast<const float4*>(kp + 4);
    float4 c2 = *reinterpret_cast<const float4*>(kp + 8);
    float4 c3 = *reinterpret_cast<const float4*>(kp + 12);
    union { unsigned u[4]; u16x8 v; } w0, w1;
    w0.u[0] = cvtpk(c0.x, c0.y); w0.u[1] = cvtpk(c0.z, c0.w);
    w0.u[2] = cvtpk(c1.x, c1.y); w0.u[3] = cvtpk(c1.z, c1.w);
    w1.u[0] = cvtpk(c2.x, c2.y); w1.u[1] = cvtpk(c2.z, c2.w);
    w1.u[2] = cvtpk(c3.x, c3.y); w1.u[3] = cvtpk(c3.z, c3.w);
    const int kc   = seg >> 4;
    const int kt2  = r >> 5;
    const int lane = r & 31;
    *reinterpret_cast<u16x8*>(ktile + ((kt2 * 4 + kc) * 64 + lane) * 16) = w0.v;
    *reinterpret_cast<u16x8*>(ktile + ((kt2 * 4 + kc) * 64 + lane + 32) * 16) = w1.v;
  }

  // ---- V: convert + LDS transpose ----
  {
    const float* vp = Vg + srow;
    float4 v0 = *reinterpret_cast<const float4*>(vp + 0);
    float4 v1 = *reinterpret_cast<const float4*>(vp + 4);
    float4 v2 = *reinterpret_cast<const float4*>(vp + 8);
    float4 v3 = *reinterpret_cast<const float4*>(vp + 12);
    float vv[16];
    vv[0] = v0.x; vv[1] = v0.y; vv[2] = v0.z; vv[3] = v0.w;
    vv[4] = v1.x; vv[5] = v1.y; vv[6] = v1.z; vv[7] = v1.w;
    vv[8] = v2.x; vv[9] = v2.y; vv[10] = v2.z; vv[11] = v2.w;
    vv[12] = v3.x; vv[13] = v3.y; vv[14] = v3.z; vv[15] = v3.w;
#pragma unroll
    for (int j = 0; j < 16; ++j)
      vt[(seg + j) * 80 + r] = (short)f2bf(vv[j]);
  }
  __syncthreads();

  // ---- V^T rows -> fragment-major write ----
  {
    const int d    = tid >> 2;
    const int kseg = (tid & 3) * 16;
    u16x8 a0 = *reinterpret_cast<const u16x8*>(vt + d * 80 + kseg);      // kv +0..7
    u16x8 a1 = *reinterpret_cast<const u16x8*>(vt + d * 80 + kseg + 8);  // kv +8..15
    const int dt2  = d >> 5;
    const int kc   = kseg >> 4;
    const int lane = d & 31;
    *reinterpret_cast<u16x8*>(vtile + ((dt2 * 4 + kc) * 64 + lane) * 16) = a0;
    *reinterpret_cast<u16x8*>(vtile + ((dt2 * 4 + kc) * 64 + lane + 32) * 16) = a1;
  }
}

// ---------------------------------------------------------------------------
// Flash attention, 32x32x16 MFMA. 1 block = 128 q-rows (4 waves x 32 q),
// KVBLK=64, double-buffered DMA staging of fragment-major blobs.
// LPT dispatch: longest q-tiles first (queue-dispatch self-balances).
// Defer-max (T13) skips the O-rescale on most tiles.
// ---------------------------------------------------------------------------
__global__ __launch_bounds__(256)
void fattn8_kernel(const float* __restrict__ Qg, const char* __restrict__ KB,
                   const char* __restrict__ VB, float* __restrict__ Og) {
  __shared__ __align__(128) char smem[32768];   // 2 bufs x (K 8K + V 8K)

  // LPT: blocks 0..63 are qt=15 (longest), ..., blocks 960..1023 are qt=0.
  // head = p & 63 keeps all 16 blocks of a head on XCD head%8 (64 % 8 == 0).
  const int p    = blockIdx.x;
  const int head = p & 63;
  const int qt   = 15 - (p >> 6);
  const int b    = head >> 4;
  const int h    = head & 15;

  const int tid = threadIdx.x;
  const int w   = tid >> 6;        // wave 0..3
  const int l   = tid & 63;
  const int q5  = l & 31;
  const int hp  = l >> 5;          // half 0/1

  const int qrow = qt * 128 + w * 32 + q5;
  const int qmin = qt * 128 + w * 32;
  const int qmax = qmin + 31;

  // ---- Q fragments (B operand: lane q=l&31, k-dim d=16kc+8hp+j), pre-scaled ----
  bf16x8 qf[4];
  {
    const float* qp = Qg + ((size_t)((b * Lc + qrow) * Hc + h)) * Dc;
#pragma unroll
    for (int kc = 0; kc < 4; ++kc) {
      const int d0 = kc * 16 + hp * 8;
      float4 a = *reinterpret_cast<const float4*>(qp + d0);
      float4 bb = *reinterpret_cast<const float4*>(qp + d0 + 4);
      union { unsigned u[4]; bf16x8 v; } f;
      f.u[0] = cvtpk(a.x * SCL, a.y * SCL);
      f.u[1] = cvtpk(a.z * SCL, a.w * SCL);
      f.u[2] = cvtpk(bb.x * SCL, bb.y * SCL);
      f.u[3] = cvtpk(bb.z * SCL, bb.w * SCL);
      qf[kc] = f.v;
    }
  }

  f32x16 o0, o1;
#pragma unroll
  for (int i = 0; i < 16; ++i) { o0[i] = 0.f; o1[i] = 0.f; }
  float m_run = -3.0e38f, l_run = 0.0f;

  const char* kbase = KB + ((size_t)head * 32) * 8192;
  const char* vbase = VB + ((size_t)head * 32) * 8192;
  const int to = tid * 16;         // per-lane global offset
  const int wl = w * 1024;         // wave-uniform LDS base offset

  auto stage = [&](int bufi, int kt) {
    const char* kb = kbase + (size_t)kt * 8192;
    const char* vb = vbase + (size_t)kt * 8192;
    char* dK = smem + bufi * 16384;
    char* dV = dK + 8192;
    glds16(kb + to, dK + wl);
    glds16(kb + 4096 + to, dK + 4096 + wl);
    glds16(vb + to, dV + wl);
    glds16(vb + 4096 + to, dV + 4096 + wl);
  };

  const int nkt = 2 * qt + 2;
  int buf = 0;
  stage(0, 0);

  for (int kt = 0; kt < nkt; ++kt) {
    if (kt + 1 < nkt) {
      stage(buf ^ 1, kt + 1);
      asm volatile("s_waitcnt vmcnt(4)" ::: "memory");
    } else {
      asm volatile("s_waitcnt vmcnt(0)" ::: "memory");
    }
    __builtin_amdgcn_s_barrier();

    const int kv0 = kt * 64;
    if (kv0 <= qmax) {               // wave-uniform skip of fully-masked tiles
      const char* smK = smem + buf * 16384;
      const char* smV = smK + 8192;

      // ---- S^T = K * Q^T (2 kv-subtiles of 32) ----
      f32x16 s0, s1;
#pragma unroll
      for (int i = 0; i < 16; ++i) { s0[i] = 0.f; s1[i] = 0.f; }
#pragma unroll
      for (int kc = 0; kc < 4; ++kc) {
        bf16x8 k0 = *reinterpret_cast<const bf16x8*>(smK + (0 * 4 + kc) * 1024 + l * 16);
        bf16x8 k1 = *reinterpret_cast<const bf16x8*>(smK + (1 * 4 + kc) * 1024 + l * 16);
        s0 = MFMA32(k0, qf[kc], s0, 0, 0, 0);
        s1 = MFMA32(k1, qf[kc], s1, 0, 0, 0);
      }

      float pv[32];
#pragma unroll
      for (int g = 0; g < 16; ++g) { pv[g] = s0[g]; pv[16 + g] = s1[g]; }

      // ---- causal mask (kv row = (g&3)+8*((g>>2)&3)+4hp+32*(g>>4)) ----
      if (kv0 + 63 > qmin) {
#pragma unroll
        for (int g = 0; g < 32; ++g) {
          const int k = (g & 3) + 8 * ((g >> 2) & 3) + 4 * hp + 32 * (g >> 4);
          if (kv0 + k > qrow) pv[g] = -3.0e38f;
        }
      }

      // ---- online softmax with defer-max (T13) ----
      float vmax = pv[0];
#pragma unroll
      for (int g = 1; g < 32; ++g) vmax = fmaxf(vmax, pv[g]);
      vmax = fmaxf(vmax, __shfl_xor(vmax, 32));
      if (!__all(vmax <= m_run + 8.0f)) {   // P bounded by 2^8; f32 accum safe
        const float m_new = fmaxf(m_run, vmax);
        const float alpha = fexp2(m_run - m_new);
        l_run *= alpha;
        m_run = m_new;
#pragma unroll
        for (int i = 0; i < 16; ++i) { o0[i] *= alpha; o1[i] *= alpha; }
      }

      float rsum = 0.f;
#pragma unroll
      for (int g = 0; g < 32; ++g) { pv[g] = fexp2(pv[g] - m_run); rsum += pv[g]; }
      rsum += __shfl_xor(rsum, 32);
      l_run += rsum;

      // ---- P -> PV B-fragments: cvt_pk + shfl_xor(32) + selects ----
      bf16x8 pf[4];
#pragma unroll
      for (int kc = 0; kc < 4; ++kc) {
        const int G = 8 * kc;
        unsigned A0 = cvtpk(pv[G + 0], pv[G + 1]);
        unsigned A1 = cvtpk(pv[G + 2], pv[G + 3]);
        unsigned B0 = cvtpk(pv[G + 4], pv[G + 5]);
        unsigned B1 = cvtpk(pv[G + 6], pv[G + 7]);
        const unsigned t0 = hp ? A0 : B0;     // what the partner lane needs
        const unsigned t1 = hp ? A1 : B1;
        const unsigned x0 = (unsigned)__shfl_xor((int)t0, 32);
        const unsigned x1 = (unsigned)__shfl_xor((int)t1, 32);
        union { unsigned u[4]; bf16x8 v; } f;
        f.u[0] = hp ? x0 : A0;   // hp0: k0,1   hp1: k8,9
        f.u[1] = hp ? x1 : A1;   // hp0: k2,3   hp1: k10,11
        f.u[2] = hp ? B0 : x0;   // hp0: k4,5   hp1: k12,13
        f.u[3] = hp ? B1 : x1;   // hp0: k6,7   hp1: k14,15
        pf[kc] = f.v;
      }

      // ---- O^T += V^T * P^T ----
#pragma unroll
      for (int kc = 0; kc < 4; ++kc) {
        bf16x8 v0 = *reinterpret_cast<const bf16x8*>(smV + (0 * 4 + kc) * 1024 + l * 16);
        bf16x8 v1 = *reinterpret_cast<const bf16x8*>(smV + (1 * 4 + kc) * 1024 + l * 16);
        o0 = MFMA32(v0, pf[kc], o0, 0, 0, 0);
        o1 = MFMA32(v1, pf[kc], o1, 0, 0, 0);
      }
    }

    __syncthreads();
    buf ^= 1;
  }

  // ---- normalize + store: lane q=l&31, d=(reg&3)+8*(reg>>2)+4hp (+32 for o1) ----
  const float inv = 1.0f / l_run;
  float* op = Og + ((size_t)((b * Lc + qrow) * Hc + h)) * Dc;
#pragma unroll
  for (int rq = 0; rq < 4; ++rq) {
    float4 st0, st1;
    st0.x = o0[4 * rq + 0] * inv; st0.y = o0[4 * rq + 1] * inv;
    st0.z = o0[4 * rq + 2] * inv; st0.w = o0[4 * rq + 3] * inv;
    st1.x = o1[4 * rq + 0] * inv; st1.y = o1[4 * rq + 1] * inv;
    st1.z = o1[4 * rq + 2] * inv; st1.w = o1[4 * rq + 3] * inv;
    *reinterpret_cast<float4*>(op + 8 * rq + 4 * hp) = st0;
    *reinterpret_cast<float4*>(op + 32 + 8 * rq + 4 * hp) = st1;
  }
}

// ---------------------------------------------------------------------------
// Fallback (ws too small): proven self-contained kernel.
// ---------------------------------------------------------------------------
__global__ __launch_bounds__(256)
void fattn_fallback(const float* __restrict__ Qg, const float* __restrict__ Kg,
                    const float* __restrict__ Vg, float* __restrict__ Og) {
  __shared__ __align__(128) char smem[32768];
  char* smK = smem;
  char* smV = smem + 16384;

  const int bid  = blockIdx.x;
  const int head = bid >> 5;
  const int qt   = bid & 31;
  const int b    = head >> 4;
  const int h    = head & 15;
  const int q0   = qt * 64;

  const int tid = threadIdx.x;
  const int w   = tid >> 6;
  const int l   = tid & 63;
  const int lo  = l & 15;
  const int hi4 = l >> 4;

  const int qrow = q0 + w * 16 + lo;
  const float* qp = Qg + ((size_t)((b * Lc + qrow) * Hc + h)) * Dc;
  bf16x8 qf[2];
#pragma unroll
  for (int dc = 0; dc < 2; ++dc) {
    float4 a = *reinterpret_cast<const float4*>(qp + dc * 32 + hi4 * 8);
    float4 c = *reinterpret_cast<const float4*>(qp + dc * 32 + hi4 * 8 + 4);
    bf16x8 f;
    f[0] = (short)f2bf(a.x * SCL); f[1] = (short)f2bf(a.y * SCL);
    f[2] = (short)f2bf(a.z * SCL); f[3] = (short)f2bf(a.w * SCL);
    f[4] = (short)f2bf(c.x * SCL); f[5] = (short)f2bf(c.y * SCL);
    f[6] = (short)f2bf(c.z * SCL); f[7] = (short)f2bf(c.w * SCL);
    qf[dc] = f;
  }

  f32x4 o[4];
#pragma unroll
  for (int dt = 0; dt < 4; ++dt) { o[dt][0] = 0.f; o[dt][1] = 0.f; o[dt][2] = 0.f; o[dt][3] = 0.f; }
  float m_run = -3.0e38f, l_run = 0.0f;

  const int sk   = tid >> 2;
  const int sd   = (tid & 3) * 16;
  const int swzK = (sk & 7) << 4;
  const int swzA = (lo & 7) << 4;

  const int nkt = qt + 1;
  for (int kt = 0; kt < nkt; ++kt) {
    const int kv0 = kt * 64;
    __syncthreads();
    {
      const float* kpr = Kg + ((size_t)((b * Lc + kv0 + sk) * Hc + h)) * Dc + sd;
      float4 c0 = *reinterpret_cast<const float4*>(kpr + 0);
      float4 c1 = *reinterpret_cast<const float4*>(kpr + 4);
      float4 c2 = *reinterpret_cast<const float4*>(kpr + 8);
      float4 c3 = *reinterpret_cast<const float4*>(kpr + 12);
      u16x8 w0, w1;
      w0[0] = f2bf(c0.x); w0[1] = f2bf(c0.y); w0[2] = f2bf(c0.z); w0[3] = f2bf(c0.w);
      w0[4] = f2bf(c1.x); w0[5] = f2bf(c1.y); w0[6] = f2bf(c1.z); w0[7] = f2bf(c1.w);
      w1[0] = f2bf(c2.x); w1[1] = f2bf(c2.y); w1[2] = f2bf(c2.z); w1[3] = f2bf(c2.w);
      w1[4] = f2bf(c3.x); w1[5] = f2bf(c3.y); w1[6] = f2bf(c3.z); w1[7] = f2bf(c3.w);
      *reinterpret_cast<u16x8*>(smK + sk * 128 + ((sd * 2) ^ swzK)) = w0;
      *reinterpret_cast<u16x8*>(smK + sk * 128 + ((sd * 2 + 16) ^ swzK)) = w1;

      const float* vpr = Vg + ((size_t)((b * Lc + kv0 + sk) * Hc + h)) * Dc + sd;
      float4 v0 = *reinterpret_cast<const float4*>(vpr + 0);
      float4 v1 = *reinterpret_cast<const float4*>(vpr + 4);
      float4 v2 = *reinterpret_cast<const float4*>(vpr + 8);
      float4 v3 = *reinterpret_cast<const float4*>(vpr + 12);
      float vv[16];
      vv[0] = v0.x; vv[1] = v0.y; vv[2] = v0.z; vv[3] = v0.w;
      vv[4] = v1.x; vv[5] = v1.y; vv[6] = v1.z; vv[7] = v1.w;
      vv[8] = v2.x; vv[9] = v2.y; vv[10] = v2.z; vv[11] = v2.w;
      vv[12] = v3.x; vv[13] = v3.y; vv[14] = v3.z; vv[15] = v3.w;
#pragma unroll
      for (int j = 0; j < 16; ++j) {
        const int d = sd + j;
        *reinterpret_cast<unsigned short*>(smV + d * 128 + ((sk * 2) ^ ((j & 7) << 4))) = f2bf(vv[j]);
      }
    }
    __syncthreads();

    f32x4 s[4];
#pragma unroll
    for (int ks = 0; ks < 4; ++ks) {
      const int rb = (ks * 16 + lo) * 128;
      bf16x8 a0 = *reinterpret_cast<const bf16x8*>(smK + rb + ((hi4 * 16) ^ swzA));
      bf16x8 a1 = *reinterpret_cast<const bf16x8*>(smK + rb + ((64 + hi4 * 16) ^ swzA));
      f32x4 c; c[0] = 0.f; c[1] = 0.f; c[2] = 0.f; c[3] = 0.f;
      c = MFMA16(a0, qf[0], c, 0, 0, 0);
      c = MFMA16(a1, qf[1], c, 0, 0, 0);
      s[ks] = c;
    }

    const bool diag = (kt == nkt - 1);
    float vmax = -3.0e38f;
#pragma unroll
    for (int ks = 0; ks < 4; ++ks) {
#pragma unroll
      for (int i = 0; i < 4; ++i) {
        float x = s[ks][i];
        if (diag) {
          const int kg = kv0 + ks * 16 + hi4 * 4 + i;
          if (kg > qrow) x = -3.0e38f;
        }
        s[ks][i] = x;
        vmax = fmaxf(vmax, x);
      }
    }
    vmax = fmaxf(vmax, __shfl_xor(vmax, 16));
    vmax = fmaxf(vmax, __shfl_xor(vmax, 32));
    const float m_new = fmaxf(m_run, vmax);
    const float alpha = fexp2(m_run - m_new);

    float rsum = 0.f;
    unsigned pk2[4][2];
#pragma unroll
    for (int ks = 0; ks < 4; ++ks) {
      const float p0 = fexp2(s[ks][0] - m_new);
      const float p1 = fexp2(s[ks][1] - m_new);
      const float p2 = fexp2(s[ks][2] - m_new);
      const float p3 = fexp2(s[ks][3] - m_new);
      rsum += (p0 + p1) + (p2 + p3);
      pk2[ks][0] = (unsigned)f2bf(p0) | ((unsigned)f2bf(p1) << 16);
      pk2[ks][1] = (unsigned)f2bf(p2) | ((unsigned)f2bf(p3) << 16);
    }
    rsum += __shfl_xor(rsum, 16);
    rsum += __shfl_xor(rsum, 32);
    l_run = l_run * alpha + rsum;
    m_run = m_new;
#pragma unroll
    for (int dt = 0; dt < 4; ++dt) {
      o[dt][0] *= alpha; o[dt][1] *= alpha; o[dt][2] *= alpha; o[dt][3] *= alpha;
    }

    const int srcA = lo + ((l & 16) << 1);
    const int srcB = srcA + 16;
    const bool up = (l & 32) != 0;
    bf16x8 pf[2];
#pragma unroll
    for (int c2 = 0; c2 < 2; ++c2) {
      const unsigned A0x = (unsigned)__shfl((int)pk2[2 * c2][0], srcA);
      const unsigned A0y = (unsigned)__shfl((int)pk2[2 * c2][1], srcA);
      const unsigned A1x = (unsigned)__shfl((int)pk2[2 * c2][0], srcB);
      const unsigned A1y = (unsigned)__shfl((int)pk2[2 * c2][1], srcB);
      const unsigned B0x = (unsigned)__shfl((int)pk2[2 * c2 + 1][0], srcA);
      const unsigned B0y = (unsigned)__shfl((int)pk2[2 * c2 + 1][1], srcA);
      const unsigned B1x = (unsigned)__shfl((int)pk2[2 * c2 + 1][0], srcB);
      const unsigned B1y = (unsigned)__shfl((int)pk2[2 * c2 + 1][1], srcB);
      union { unsigned u[4]; bf16x8 v; } cvt;
      cvt.u[0] = up ? B0x : A0x;
      cvt.u[1] = up ? B0y : A0y;
      cvt.u[2] = up ? B1x : A1x;
      cvt.u[3] = up ? B1y : A1y;
      pf[c2] = cvt.v;
    }

#pragma unroll
    for (int dt = 0; dt < 4; ++dt) {
      const int rb = (dt * 16 + lo) * 128;
#pragma unroll
      for (int c2 = 0; c2 < 2; ++c2) {
        bf16x8 vf = *reinterpret_cast<const bf16x8*>(smV + rb + ((c2 * 64 + hi4 * 16) ^ swzA));
        o[dt] = MFMA16(vf, pf[c2], o[dt], 0, 0, 0);
      }
    }
  }

  const float inv = 1.0f / l_run;
  float* op = Og + ((size_t)((b * Lc + qrow) * Hc + h)) * Dc;
#pragma unroll
  for (int dt = 0; dt < 4; ++dt) {
    float4 st;
    st.x = o[dt][0] * inv; st.y = o[dt][1] * inv;
    st.z = o[dt][2] * inv; st.w = o[dt][3] * inv;
    *reinterpret_cast<float4*>(op + dt * 16 + hi4 * 4) = st;
  }
}

extern "C" void kernel_launch(void* const* d_in, const int* in_sizes, int n_in,
                              void* d_out, int out_size, void* d_ws, size_t ws_size,
                              hipStream_t stream) {
  const float* Qg = (const float*)d_in[0];
  const float* Kg = (const float*)d_in[1];
  const float* Vg = (const float*)d_in[2];
  float* Og = (float*)d_out;

  const size_t blob_bytes = (size_t)64 * 32 * 8192;   // 16.78 MB per tensor
  if (ws_size >= 2 * blob_bytes) {
    char* KB = (char*)d_ws;
    char* VB = KB + blob_bytes;
    hipLaunchKernelGGL(prep6_kernel, dim3(2048), dim3(256), 0, stream, Kg, Vg, KB, VB);
    hipLaunchKernelGGL(fattn8_kernel, dim3(1024), dim3(256), 0, stream, Qg, KB, VB, Og);
  } else {
    hipLaunchKernelGGL(fattn_fallback, dim3(2048), dim3(256), 0, stream, Qg, Kg, Vg, Og);
  }
}